// Round 1
// baseline (1043.812 us; speedup 1.0000x reference)
//
#include <hip/hip_runtime.h>
#include <math.h>

#define NN 50000
#define EE 800000
#define INCH 512
#define C1 256     // H1*HID
#define NC 16
#define NEG 0.2f

__device__ inline void atomAddF(float* p, float v) {
    __hip_atomic_fetch_add(p, v, __ATOMIC_RELAXED, __HIP_MEMORY_SCOPE_AGENT);
}

// ---------------- GEMM1: h1[50000,256] = x[50000,512] @ W1[512,256] ----------------
__global__ __launch_bounds__(256) void k_gemm1(const float* __restrict__ x,
                                               const float* __restrict__ W,
                                               float* __restrict__ h1) {
    __shared__ float As[16][64];
    __shared__ float Bs[16][64];
    int tid = threadIdx.x;
    int tx = tid & 15, ty = tid >> 4;
    int bm = blockIdx.x * 64;
    int bn = blockIdx.y * 64;
    float acc[4][4] = {};
    int la_k = tid & 15;   // k within tile
    int la_m = tid >> 4;   // row, step 16
    int lb_n = tid & 63;
    int lb_k = tid >> 6;   // 0..3, step 4

    for (int kt = 0; kt < INCH; kt += 16) {
#pragma unroll
        for (int i = 0; i < 4; i++) {
            int m = bm + la_m + 16 * i;
            As[la_k][la_m + 16 * i] = (m < NN) ? x[(size_t)m * INCH + kt + la_k] : 0.f;
        }
#pragma unroll
        for (int i = 0; i < 4; i++) {
            Bs[lb_k + 4 * i][lb_n] = W[(size_t)(kt + lb_k + 4 * i) * C1 + bn + lb_n];
        }
        __syncthreads();
#pragma unroll
        for (int kk = 0; kk < 16; kk++) {
            float a[4], b[4];
#pragma unroll
            for (int i = 0; i < 4; i++) a[i] = As[kk][ty * 4 + i];
#pragma unroll
            for (int j = 0; j < 4; j++) b[j] = Bs[kk][tx * 4 + j];
#pragma unroll
            for (int i = 0; i < 4; i++)
#pragma unroll
                for (int j = 0; j < 4; j++) acc[i][j] += a[i] * b[j];
        }
        __syncthreads();
    }
#pragma unroll
    for (int i = 0; i < 4; i++) {
        int m = bm + ty * 4 + i;
        if (m < NN) {
            float4 v = make_float4(acc[i][0], acc[i][1], acc[i][2], acc[i][3]);
            *(float4*)&h1[(size_t)m * C1 + bn + tx * 4] = v;
        }
    }
}

// ---------------- per-node attention logits (layer 1) ----------------
__global__ __launch_bounds__(256) void k_att1(const float* __restrict__ h1,
                                              const float* __restrict__ as,  // [256] flat
                                              const float* __restrict__ ad,
                                              float* __restrict__ a_src,
                                              float* __restrict__ a_dst) {
    int n = blockIdx.x;
    int c = threadIdx.x;
    float v = h1[(size_t)n * C1 + c];
    float ps = v * as[c];
    float pd = v * ad[c];
#pragma unroll
    for (int off = 32; off > 0; off >>= 1) {
        ps += __shfl_down(ps, off, 64);
        pd += __shfl_down(pd, off, 64);
    }
    if ((c & 63) == 0) {
        int h = c >> 6;
        a_src[n * 4 + h] = ps;
        a_dst[n * 4 + h] = pd;
    }
}

// ---------------- edge exp-logits + denom + degree histogram (layer 1) ----------------
__global__ __launch_bounds__(256) void k_edge1(const int* __restrict__ esrc, const int* __restrict__ edst,
                                               const float* __restrict__ a_src, const float* __restrict__ a_dst,
                                               float* __restrict__ exnum, float* __restrict__ esum,
                                               int* __restrict__ cnt) {
    int i = blockIdx.x * 256 + threadIdx.x;
    if (i >= EE + NN) return;
    int s, d;
    if (i < EE) { s = esrc[i]; d = edst[i]; } else { s = i - EE; d = s; }
    float4 vs = *(const float4*)&a_src[s * 4];
    float4 vd = *(const float4*)&a_dst[d * 4];
    float e0 = vs.x + vd.x, e1 = vs.y + vd.y, e2 = vs.z + vd.z, e3 = vs.w + vd.w;
    e0 = e0 >= 0.f ? e0 : NEG * e0;
    e1 = e1 >= 0.f ? e1 : NEG * e1;
    e2 = e2 >= 0.f ? e2 : NEG * e2;
    e3 = e3 >= 0.f ? e3 : NEG * e3;
    float x0 = __expf(e0), x1 = __expf(e1), x2 = __expf(e2), x3 = __expf(e3);
    *(float4*)&exnum[(size_t)i * 4] = make_float4(x0, x1, x2, x3);
    atomAddF(&esum[d * 4 + 0], x0);
    atomAddF(&esum[d * 4 + 1], x1);
    atomAddF(&esum[d * 4 + 2], x2);
    atomAddF(&esum[d * 4 + 3], x3);
    if (i < EE) atomicAdd(&cnt[d], 1);
}

// ---------------- scan (3-phase exclusive prefix over cnt[50000]) ----------------
__global__ __launch_bounds__(256) void k_scan1(const int* __restrict__ cnt, int* __restrict__ partial) {
    __shared__ int s[256];
    int i = blockIdx.x * 256 + threadIdx.x;
    s[threadIdx.x] = (i < NN) ? cnt[i] : 0;
    __syncthreads();
    for (int off = 128; off; off >>= 1) {
        if (threadIdx.x < off) s[threadIdx.x] += s[threadIdx.x + off];
        __syncthreads();
    }
    if (threadIdx.x == 0) partial[blockIdx.x] = s[0];
}

__global__ __launch_bounds__(256) void k_scan2(int* partial, int nb) {
    __shared__ int s[256];
    int t = threadIdx.x;
    int v = (t < nb) ? partial[t] : 0;
    s[t] = v;
    __syncthreads();
    for (int off = 1; off < 256; off <<= 1) {
        int y = (t >= off) ? s[t - off] : 0;
        __syncthreads();
        s[t] += y;
        __syncthreads();
    }
    if (t < nb) partial[t] = s[t] - v;  // exclusive
}

__global__ __launch_bounds__(256) void k_scan3(const int* __restrict__ cnt, const int* __restrict__ partial,
                                               int* __restrict__ row_off, int* __restrict__ cursor) {
    __shared__ int s[256];
    int t = threadIdx.x;
    int i = blockIdx.x * 256 + t;
    int v = (i < NN) ? cnt[i] : 0;
    s[t] = v;
    __syncthreads();
    for (int off = 1; off < 256; off <<= 1) {
        int y = (t >= off) ? s[t - off] : 0;
        __syncthreads();
        s[t] += y;
        __syncthreads();
    }
    if (i < NN) {
        int o = partial[blockIdx.x] + s[t] - v;
        row_off[i] = o;
        cursor[i] = o;
    }
}

// ---------------- CSR placement ----------------
__global__ __launch_bounds__(256) void k_place(const int* __restrict__ edst, int* __restrict__ cursor,
                                               int* __restrict__ csr) {
    int e = blockIdx.x * 256 + threadIdx.x;
    if (e >= EE) return;
    int d = edst[e];
    int pos = atomicAdd(&cursor[d], 1);
    csr[pos] = e;
}

// ---------------- layer-1 aggregation + bias + ELU ----------------
__global__ __launch_bounds__(256) void k_agg1(const float* __restrict__ h1,
                                              const int* __restrict__ esrc, const int* __restrict__ csr,
                                              const int* __restrict__ row_off, const int* __restrict__ cnt,
                                              const float* __restrict__ exnum, const float* __restrict__ esum,
                                              const float* __restrict__ b1, float* __restrict__ h2in) {
    int n = blockIdx.x;
    int c = threadIdx.x;
    int h = c >> 6;
    float inv = 1.f / esum[n * 4 + h];
    float acc = exnum[(size_t)(EE + n) * 4 + h] * h1[(size_t)n * C1 + c];
    int base = row_off[n], deg = cnt[n];
    for (int k = 0; k < deg; k++) {
        int eid = csr[base + k];
        int s = esrc[eid];
        acc += exnum[(size_t)eid * 4 + h] * h1[(size_t)s * C1 + c];
    }
    float val = acc * inv + b1[c];
    h2in[(size_t)n * C1 + c] = val > 0.f ? val : expm1f(val);
}

// ---------------- GEMM2 + layer-2 attention logits ----------------
__global__ __launch_bounds__(256) void k_gemm2(const float* __restrict__ h2in,
                                               const float* __restrict__ W2,
                                               const float* __restrict__ as2, const float* __restrict__ ad2,
                                               float* __restrict__ h2,
                                               float* __restrict__ a_src2, float* __restrict__ a_dst2) {
    __shared__ float ws[256 * 16];
    __shared__ float hs[16 * 256];
    int tid = threadIdx.x;
#pragma unroll
    for (int i = 0; i < 16; i++) ws[i * 256 + tid] = W2[i * 256 + tid];
    int nb = blockIdx.x * 16;
    for (int i = 0; i < 16; i++) {
        int n = nb + i;
        hs[i * 256 + tid] = (n < NN) ? h2in[(size_t)n * C1 + tid] : 0.f;
    }
    __syncthreads();
    int r = tid >> 4, col = tid & 15;
    float acc = 0.f;
    for (int k = 0; k < 256; k++) acc += hs[r * 256 + k] * ws[k * 16 + col];
    float pa = acc * as2[col], pb = acc * ad2[col];
#pragma unroll
    for (int off = 8; off; off >>= 1) {
        pa += __shfl_xor(pa, off, 16);
        pb += __shfl_xor(pb, off, 16);
    }
    int n = nb + r;
    if (n < NN) {
        h2[(size_t)n * NC + col] = acc;
        if (col == 0) { a_src2[n] = pa; a_dst2[n] = pb; }
    }
}

// ---------------- edge exp-logits + denom (layer 2, 1 head) ----------------
__global__ __launch_bounds__(256) void k_edge2(const int* __restrict__ esrc, const int* __restrict__ edst,
                                               const float* __restrict__ a_src, const float* __restrict__ a_dst,
                                               float* __restrict__ exnum, float* __restrict__ esum) {
    int i = blockIdx.x * 256 + threadIdx.x;
    if (i >= EE + NN) return;
    int s, d;
    if (i < EE) { s = esrc[i]; d = edst[i]; } else { s = i - EE; d = s; }
    float e = a_src[s] + a_dst[d];
    e = e >= 0.f ? e : NEG * e;
    float x = __expf(e);
    exnum[i] = x;
    atomAddF(&esum[d], x);
}

// ---------------- layer-2 aggregation + bias -> out ----------------
__global__ __launch_bounds__(256) void k_agg2(const float* __restrict__ h2,
                                              const int* __restrict__ esrc, const int* __restrict__ csr,
                                              const int* __restrict__ row_off, const int* __restrict__ cnt,
                                              const float* __restrict__ exnum, const float* __restrict__ esum,
                                              const float* __restrict__ b2, float* __restrict__ out) {
    int tid = threadIdx.x;
    int r = tid >> 4, col = tid & 15;
    int n = blockIdx.x * 16 + r;
    if (n >= NN) return;
    float inv = 1.f / esum[n];
    float acc = exnum[EE + n] * h2[(size_t)n * NC + col];
    int base = row_off[n], deg = cnt[n];
    for (int k = 0; k < deg; k++) {
        int eid = csr[base + k];
        acc += exnum[eid] * h2[(size_t)esrc[eid] * NC + col];
    }
    out[(size_t)n * NC + col] = acc * inv + b2[col];
}

extern "C" void kernel_launch(void* const* d_in, const int* in_sizes, int n_in,
                              void* d_out, int out_size, void* d_ws, size_t ws_size,
                              hipStream_t stream) {
    const float* x   = (const float*)d_in[0];
    const int*   ei  = (const int*)d_in[1];
    const int*   esrc = ei;
    const int*   edst = ei + EE;
    const float* W1  = (const float*)d_in[2];
    const float* as1 = (const float*)d_in[3];
    const float* ad1 = (const float*)d_in[4];
    const float* b1  = (const float*)d_in[5];
    const float* W2  = (const float*)d_in[6];
    const float* as2 = (const float*)d_in[7];
    const float* ad2 = (const float*)d_in[8];
    const float* b2  = (const float*)d_in[9];
    float* out = (float*)d_out;

    char* w = (char*)d_ws;
    size_t off = 0;
    auto alloc = [&](size_t bytes) -> void* {
        void* p = w + off;
        off += (bytes + 255) & ~(size_t)255;
        return p;
    };
    float* h1     = (float*)alloc((size_t)NN * C1 * 4);
    float* h2in   = (float*)alloc((size_t)NN * C1 * 4);
    float* exnum1 = (float*)alloc((size_t)(EE + NN) * 4 * 4);
    int*   csr    = (int*)alloc((size_t)EE * 4);
    float* exnum2 = (float*)alloc((size_t)(EE + NN) * 4);
    float* h2     = (float*)alloc((size_t)NN * NC * 4);
    float* a_src1 = (float*)alloc((size_t)NN * 4 * 4);
    float* a_dst1 = (float*)alloc((size_t)NN * 4 * 4);
    float* esum1  = (float*)alloc((size_t)NN * 4 * 4);
    int*   cnt    = (int*)alloc((size_t)NN * 4);
    int*   row_off= (int*)alloc((size_t)NN * 4);
    int*   cursor = (int*)alloc((size_t)NN * 4);
    float* a_src2 = (float*)alloc((size_t)NN * 4);
    float* a_dst2 = (float*)alloc((size_t)NN * 4);
    float* esum2  = (float*)alloc((size_t)NN * 4);
    int*   partial= (int*)alloc(256 * 4);

    hipMemsetAsync(esum1, 0, (size_t)NN * 4 * 4, stream);
    hipMemsetAsync(cnt, 0, (size_t)NN * 4, stream);
    hipMemsetAsync(esum2, 0, (size_t)NN * 4, stream);

    const int NBLK = (NN + 255) / 256;          // 196
    const int EBLK = (EE + NN + 255) / 256;     // 3321

    dim3 g1((NN + 63) / 64, C1 / 64);
    k_gemm1<<<g1, 256, 0, stream>>>(x, W1, h1);
    k_att1<<<NN, 256, 0, stream>>>(h1, as1, ad1, a_src1, a_dst1);
    k_edge1<<<EBLK, 256, 0, stream>>>(esrc, edst, a_src1, a_dst1, exnum1, esum1, cnt);
    k_scan1<<<NBLK, 256, 0, stream>>>(cnt, partial);
    k_scan2<<<1, 256, 0, stream>>>(partial, NBLK);
    k_scan3<<<NBLK, 256, 0, stream>>>(cnt, partial, row_off, cursor);
    k_place<<<(EE + 255) / 256, 256, 0, stream>>>(edst, cursor, csr);
    k_agg1<<<NN, 256, 0, stream>>>(h1, esrc, csr, row_off, cnt, exnum1, esum1, b1, h2in);
    k_gemm2<<<(NN + 15) / 16, 256, 0, stream>>>(h2in, W2, as2, ad2, h2, a_src2, a_dst2);
    k_edge2<<<EBLK, 256, 0, stream>>>(esrc, edst, a_src2, a_dst2, exnum2, esum2);
    k_agg2<<<(NN + 15) / 16, 256, 0, stream>>>(h2, esrc, csr, row_off, cnt, exnum2, esum2, b2, out);
}

// Round 2
// 893.570 us; speedup vs baseline: 1.1681x; 1.1681x over previous
//
#include <hip/hip_runtime.h>
#include <math.h>

#define NN 50000
#define EE 800000
#define INCH 512
#define C1 256     // H1*HID
#define NC 16
#define NEG 0.2f

__device__ inline void atomAddF(float* p, float v) {
    __hip_atomic_fetch_add(p, v, __ATOMIC_RELAXED, __HIP_MEMORY_SCOPE_AGENT);
}

// ---------------- GEMM1: h1[50000,256] = x[50000,512] @ W1[512,256] ----------------
// Fused: per-node attention logits for this head (blockIdx.y == head).
#define LDA 68   // padded LDS stride (conflict-free staging writes + b128 reads)
__global__ __launch_bounds__(256) void k_gemm1(const float* __restrict__ x,
                                               const float* __restrict__ W,
                                               const float* __restrict__ as1,
                                               const float* __restrict__ ad1,
                                               float* __restrict__ h1,
                                               float* __restrict__ a_src,
                                               float* __restrict__ a_dst) {
    __shared__ __align__(16) float As[16 * LDA];
    __shared__ __align__(16) float Bs[16 * LDA];
    int tid = threadIdx.x;
    int tx = tid & 15, ty = tid >> 4;
    int bm = blockIdx.x * 64;
    int bn = blockIdx.y * 64;   // head = blockIdx.y
    float acc[4][4] = {};
    int la_k = tid & 15;   // k within tile
    int la_m = tid >> 4;   // row, step 16
    int lb_n = tid & 63;
    int lb_k = tid >> 6;   // 0..3, step 4

    for (int kt = 0; kt < INCH; kt += 16) {
#pragma unroll
        for (int i = 0; i < 4; i++) {
            int m = bm + la_m + 16 * i;
            As[la_k * LDA + la_m + 16 * i] = (m < NN) ? x[(size_t)m * INCH + kt + la_k] : 0.f;
        }
#pragma unroll
        for (int i = 0; i < 4; i++) {
            Bs[(lb_k + 4 * i) * LDA + lb_n] = W[(size_t)(kt + lb_k + 4 * i) * C1 + bn + lb_n];
        }
        __syncthreads();
#pragma unroll
        for (int kk = 0; kk < 16; kk++) {
            float4 a = *(const float4*)&As[kk * LDA + ty * 4];
            float4 b = *(const float4*)&Bs[kk * LDA + tx * 4];
            acc[0][0] += a.x * b.x; acc[0][1] += a.x * b.y; acc[0][2] += a.x * b.z; acc[0][3] += a.x * b.w;
            acc[1][0] += a.y * b.x; acc[1][1] += a.y * b.y; acc[1][2] += a.y * b.z; acc[1][3] += a.y * b.w;
            acc[2][0] += a.z * b.x; acc[2][1] += a.z * b.y; acc[2][2] += a.z * b.z; acc[2][3] += a.z * b.w;
            acc[3][0] += a.w * b.x; acc[3][1] += a.w * b.y; acc[3][2] += a.w * b.z; acc[3][3] += a.w * b.w;
        }
        __syncthreads();
    }
    // store h1 tile
#pragma unroll
    for (int i = 0; i < 4; i++) {
        int m = bm + ty * 4 + i;
        if (m < NN) {
            float4 v = make_float4(acc[i][0], acc[i][1], acc[i][2], acc[i][3]);
            *(float4*)&h1[(size_t)m * C1 + bn + tx * 4] = v;
        }
    }
    // fused attention logits: reduce over this head's 64 cols (16 tx lanes x 4 each)
    float as0 = as1[bn + tx * 4 + 0], asx1 = as1[bn + tx * 4 + 1], as2 = as1[bn + tx * 4 + 2], as3 = as1[bn + tx * 4 + 3];
    float ad0 = ad1[bn + tx * 4 + 0], adx1 = ad1[bn + tx * 4 + 1], ad2 = ad1[bn + tx * 4 + 2], ad3 = ad1[bn + tx * 4 + 3];
#pragma unroll
    for (int i = 0; i < 4; i++) {
        float ps = acc[i][0] * as0 + acc[i][1] * asx1 + acc[i][2] * as2 + acc[i][3] * as3;
        float pd = acc[i][0] * ad0 + acc[i][1] * adx1 + acc[i][2] * ad2 + acc[i][3] * ad3;
#pragma unroll
        for (int off = 8; off; off >>= 1) {
            ps += __shfl_xor(ps, off, 16);
            pd += __shfl_xor(pd, off, 16);
        }
        if (tx == 0) {
            int m = bm + ty * 4 + i;
            if (m < NN) {
                a_src[m * 4 + blockIdx.y] = ps;
                a_dst[m * 4 + blockIdx.y] = pd;
            }
        }
    }
}

// ---------------- edge exp-logits + denom + degree histogram (layer 1) ----------------
__global__ __launch_bounds__(256) void k_edge1(const int* __restrict__ esrc, const int* __restrict__ edst,
                                               const float* __restrict__ a_src, const float* __restrict__ a_dst,
                                               float* __restrict__ exnum, float* __restrict__ self1,
                                               float* __restrict__ esum, int* __restrict__ cnt) {
    int i = blockIdx.x * 256 + threadIdx.x;
    if (i >= EE + NN) return;
    int s, d;
    if (i < EE) { s = esrc[i]; d = edst[i]; } else { s = i - EE; d = s; }
    float4 vs = *(const float4*)&a_src[s * 4];
    float4 vd = *(const float4*)&a_dst[d * 4];
    float e0 = vs.x + vd.x, e1 = vs.y + vd.y, e2 = vs.z + vd.z, e3 = vs.w + vd.w;
    e0 = e0 >= 0.f ? e0 : NEG * e0;
    e1 = e1 >= 0.f ? e1 : NEG * e1;
    e2 = e2 >= 0.f ? e2 : NEG * e2;
    e3 = e3 >= 0.f ? e3 : NEG * e3;
    float x0 = __expf(e0), x1 = __expf(e1), x2 = __expf(e2), x3 = __expf(e3);
    if (i < EE) *(float4*)&exnum[(size_t)i * 4] = make_float4(x0, x1, x2, x3);
    else        *(float4*)&self1[(size_t)(i - EE) * 4] = make_float4(x0, x1, x2, x3);
    atomAddF(&esum[d * 4 + 0], x0);
    atomAddF(&esum[d * 4 + 1], x1);
    atomAddF(&esum[d * 4 + 2], x2);
    atomAddF(&esum[d * 4 + 3], x3);
    if (i < EE) atomicAdd(&cnt[d], 1);
}

// ---------------- scan (3-phase exclusive prefix over cnt[50000]) ----------------
__global__ __launch_bounds__(256) void k_scan1(const int* __restrict__ cnt, int* __restrict__ partial) {
    __shared__ int s[256];
    int i = blockIdx.x * 256 + threadIdx.x;
    s[threadIdx.x] = (i < NN) ? cnt[i] : 0;
    __syncthreads();
    for (int off = 128; off; off >>= 1) {
        if (threadIdx.x < off) s[threadIdx.x] += s[threadIdx.x + off];
        __syncthreads();
    }
    if (threadIdx.x == 0) partial[blockIdx.x] = s[0];
}

__global__ __launch_bounds__(256) void k_scan2(int* partial, int nb) {
    __shared__ int s[256];
    int t = threadIdx.x;
    int v = (t < nb) ? partial[t] : 0;
    s[t] = v;
    __syncthreads();
    for (int off = 1; off < 256; off <<= 1) {
        int y = (t >= off) ? s[t - off] : 0;
        __syncthreads();
        s[t] += y;
        __syncthreads();
    }
    if (t < nb) partial[t] = s[t] - v;  // exclusive
}

__global__ __launch_bounds__(256) void k_scan3(const int* __restrict__ cnt, const int* __restrict__ partial,
                                               int* __restrict__ row_off, int* __restrict__ cursor) {
    __shared__ int s[256];
    int t = threadIdx.x;
    int i = blockIdx.x * 256 + t;
    int v = (i < NN) ? cnt[i] : 0;
    s[t] = v;
    __syncthreads();
    for (int off = 1; off < 256; off <<= 1) {
        int y = (t >= off) ? s[t - off] : 0;
        __syncthreads();
        s[t] += y;
        __syncthreads();
    }
    if (i < NN) {
        int o = partial[blockIdx.x] + s[t] - v;
        row_off[i] = o;
        cursor[i] = o;
    }
}

// ---------------- CSR placement ----------------
__global__ __launch_bounds__(256) void k_place(const int* __restrict__ edst, int* __restrict__ cursor,
                                               int* __restrict__ csr) {
    int e = blockIdx.x * 256 + threadIdx.x;
    if (e >= EE) return;
    int d = edst[e];
    int pos = atomicAdd(&cursor[d], 1);
    csr[pos] = e;
}

// ---------------- layer-1 aggregation + bias + ELU (4-wide unrolled MLP) ----------------
__global__ __launch_bounds__(256) void k_agg1(const float* __restrict__ h1,
                                              const int* __restrict__ esrc, const int* __restrict__ csr,
                                              const int* __restrict__ row_off, const int* __restrict__ cnt,
                                              const float* __restrict__ exnum, const float* __restrict__ self1,
                                              const float* __restrict__ esum,
                                              const float* __restrict__ b1, float* __restrict__ h2in) {
    int n = blockIdx.x;
    int c = threadIdx.x;
    int h = c >> 6;
    float inv = 1.f / esum[n * 4 + h];
    float acc = self1[(size_t)n * 4 + h] * h1[(size_t)n * C1 + c];
    int base = row_off[n], deg = cnt[n];
    int k = 0;
    for (; k + 4 <= deg; k += 4) {
        int e0 = csr[base + k + 0], e1 = csr[base + k + 1], e2 = csr[base + k + 2], e3 = csr[base + k + 3];
        int s0 = esrc[e0], s1 = esrc[e1], s2 = esrc[e2], s3 = esrc[e3];
        float w0 = exnum[(size_t)e0 * 4 + h], w1 = exnum[(size_t)e1 * 4 + h];
        float w2 = exnum[(size_t)e2 * 4 + h], w3 = exnum[(size_t)e3 * 4 + h];
        float v0 = h1[(size_t)s0 * C1 + c], v1 = h1[(size_t)s1 * C1 + c];
        float v2 = h1[(size_t)s2 * C1 + c], v3 = h1[(size_t)s3 * C1 + c];
        acc += w0 * v0;
        acc += w1 * v1;
        acc += w2 * v2;
        acc += w3 * v3;
    }
    for (; k < deg; k++) {
        int e0 = csr[base + k];
        int s0 = esrc[e0];
        acc += exnum[(size_t)e0 * 4 + h] * h1[(size_t)s0 * C1 + c];
    }
    float val = acc * inv + b1[c];
    h2in[(size_t)n * C1 + c] = val > 0.f ? val : expm1f(val);
}

// ---------------- GEMM2 + layer-2 attention logits ----------------
#define LDB 260
__global__ __launch_bounds__(256) void k_gemm2(const float* __restrict__ h2in,
                                               const float* __restrict__ W2,
                                               const float* __restrict__ as2, const float* __restrict__ ad2,
                                               float* __restrict__ h2,
                                               float* __restrict__ a_src2, float* __restrict__ a_dst2) {
    __shared__ __align__(16) float ws_t[16 * LDB];  // [col][k]
    __shared__ __align__(16) float hs[16 * LDB];    // [r][k]
    int tid = threadIdx.x;
#pragma unroll
    for (int i = 0; i < 16; i++) {
        int idx = i * 256 + tid;
        int k = idx >> 4, col = idx & 15;
        ws_t[col * LDB + k] = W2[idx];
    }
    int nb = blockIdx.x * 16;
    for (int i = 0; i < 16; i++) {
        int n = nb + i;
        hs[i * LDB + tid] = (n < NN) ? h2in[(size_t)n * C1 + tid] : 0.f;
    }
    __syncthreads();
    int r = tid >> 4, col = tid & 15;
    float acc = 0.f;
    for (int k = 0; k < 256; k += 4) {
        float4 hv = *(const float4*)&hs[r * LDB + k];
        float4 wv = *(const float4*)&ws_t[col * LDB + k];
        acc += hv.x * wv.x + hv.y * wv.y + hv.z * wv.z + hv.w * wv.w;
    }
    float pa = acc * as2[col], pb = acc * ad2[col];
#pragma unroll
    for (int off = 8; off; off >>= 1) {
        pa += __shfl_xor(pa, off, 16);
        pb += __shfl_xor(pb, off, 16);
    }
    int n = nb + r;
    if (n < NN) {
        h2[(size_t)n * NC + col] = acc;
        if (col == 0) { a_src2[n] = pa; a_dst2[n] = pb; }
    }
}

// ---------------- edge exp-logits + denom (layer 2, 1 head) ----------------
__global__ __launch_bounds__(256) void k_edge2(const int* __restrict__ esrc, const int* __restrict__ edst,
                                               const float* __restrict__ a_src, const float* __restrict__ a_dst,
                                               float* __restrict__ exnum, float* __restrict__ self2,
                                               float* __restrict__ esum) {
    int i = blockIdx.x * 256 + threadIdx.x;
    if (i >= EE + NN) return;
    int s, d;
    if (i < EE) { s = esrc[i]; d = edst[i]; } else { s = i - EE; d = s; }
    float e = a_src[s] + a_dst[d];
    e = e >= 0.f ? e : NEG * e;
    float x = __expf(e);
    if (i < EE) exnum[i] = x;
    else        self2[i - EE] = x;
    atomAddF(&esum[d], x);
}

// ---------------- layer-2 aggregation + bias -> out (4-wide unrolled) ----------------
__global__ __launch_bounds__(256) void k_agg2(const float* __restrict__ h2,
                                              const int* __restrict__ esrc, const int* __restrict__ csr,
                                              const int* __restrict__ row_off, const int* __restrict__ cnt,
                                              const float* __restrict__ exnum, const float* __restrict__ self2,
                                              const float* __restrict__ esum,
                                              const float* __restrict__ b2, float* __restrict__ out) {
    int tid = threadIdx.x;
    int r = tid >> 4, col = tid & 15;
    int n = blockIdx.x * 16 + r;
    if (n >= NN) return;
    float inv = 1.f / esum[n];
    float acc = self2[n] * h2[(size_t)n * NC + col];
    int base = row_off[n], deg = cnt[n];
    int k = 0;
    for (; k + 4 <= deg; k += 4) {
        int e0 = csr[base + k + 0], e1 = csr[base + k + 1], e2 = csr[base + k + 2], e3 = csr[base + k + 3];
        int s0 = esrc[e0], s1 = esrc[e1], s2 = esrc[e2], s3 = esrc[e3];
        float w0 = exnum[e0], w1 = exnum[e1], w2 = exnum[e2], w3 = exnum[e3];
        float v0 = h2[(size_t)s0 * NC + col], v1 = h2[(size_t)s1 * NC + col];
        float v2 = h2[(size_t)s2 * NC + col], v3 = h2[(size_t)s3 * NC + col];
        acc += w0 * v0;
        acc += w1 * v1;
        acc += w2 * v2;
        acc += w3 * v3;
    }
    for (; k < deg; k++) {
        int e0 = csr[base + k];
        acc += exnum[e0] * h2[(size_t)esrc[e0] * NC + col];
    }
    out[(size_t)n * NC + col] = acc * inv + b2[col];
}

extern "C" void kernel_launch(void* const* d_in, const int* in_sizes, int n_in,
                              void* d_out, int out_size, void* d_ws, size_t ws_size,
                              hipStream_t stream) {
    const float* x   = (const float*)d_in[0];
    const int*   ei  = (const int*)d_in[1];
    const int*   esrc = ei;
    const int*   edst = ei + EE;
    const float* W1  = (const float*)d_in[2];
    const float* as1 = (const float*)d_in[3];
    const float* ad1 = (const float*)d_in[4];
    const float* b1  = (const float*)d_in[5];
    const float* W2  = (const float*)d_in[6];
    const float* as2 = (const float*)d_in[7];
    const float* ad2 = (const float*)d_in[8];
    const float* b2  = (const float*)d_in[9];
    float* out = (float*)d_out;

    char* w = (char*)d_ws;
    size_t off = 0;
    auto alloc = [&](size_t bytes) -> void* {
        void* p = w + off;
        off += (bytes + 255) & ~(size_t)255;
        return p;
    };
    float* h1     = (float*)alloc((size_t)NN * C1 * 4);
    float* h2in   = (float*)alloc((size_t)NN * C1 * 4);
    float* exnum1 = (float*)alloc((size_t)EE * 4 * 4);
    float* self1  = (float*)alloc((size_t)NN * 4 * 4);
    int*   csr    = (int*)alloc((size_t)EE * 4);
    float* exnum2 = (float*)alloc((size_t)EE * 4);
    float* self2  = (float*)alloc((size_t)NN * 4);
    float* h2     = (float*)alloc((size_t)NN * NC * 4);
    float* a_src1 = (float*)alloc((size_t)NN * 4 * 4);
    float* a_dst1 = (float*)alloc((size_t)NN * 4 * 4);
    float* esum1  = (float*)alloc((size_t)NN * 4 * 4);
    int*   cnt    = (int*)alloc((size_t)NN * 4);
    int*   row_off= (int*)alloc((size_t)NN * 4);
    int*   cursor = (int*)alloc((size_t)NN * 4);
    float* a_src2 = (float*)alloc((size_t)NN * 4);
    float* a_dst2 = (float*)alloc((size_t)NN * 4);
    float* esum2  = (float*)alloc((size_t)NN * 4);
    int*   partial= (int*)alloc(256 * 4);

    hipMemsetAsync(esum1, 0, (size_t)NN * 4 * 4, stream);
    hipMemsetAsync(cnt, 0, (size_t)NN * 4, stream);
    hipMemsetAsync(esum2, 0, (size_t)NN * 4, stream);

    const int NBLK = (NN + 255) / 256;          // 196
    const int EBLK = (EE + NN + 255) / 256;     // 3321

    dim3 g1((NN + 63) / 64, C1 / 64);
    k_gemm1<<<g1, 256, 0, stream>>>(x, W1, as1, ad1, h1, a_src1, a_dst1);
    k_edge1<<<EBLK, 256, 0, stream>>>(esrc, edst, a_src1, a_dst1, exnum1, self1, esum1, cnt);
    k_scan1<<<NBLK, 256, 0, stream>>>(cnt, partial);
    k_scan2<<<1, 256, 0, stream>>>(partial, NBLK);
    k_scan3<<<NBLK, 256, 0, stream>>>(cnt, partial, row_off, cursor);
    k_place<<<(EE + 255) / 256, 256, 0, stream>>>(edst, cursor, csr);
    k_agg1<<<NN, 256, 0, stream>>>(h1, esrc, csr, row_off, cnt, exnum1, self1, esum1, b1, h2in);
    k_gemm2<<<(NN + 15) / 16, 256, 0, stream>>>(h2in, W2, as2, ad2, h2, a_src2, a_dst2);
    k_edge2<<<EBLK, 256, 0, stream>>>(esrc, edst, a_src2, a_dst2, exnum2, self2, esum2);
    k_agg2<<<(NN + 15) / 16, 256, 0, stream>>>(h2, esrc, csr, row_off, cnt, exnum2, self2, esum2, b2, out);
}

// Round 3
// 767.022 us; speedup vs baseline: 1.3609x; 1.1650x over previous
//
#include <hip/hip_runtime.h>
#include <hip/hip_bf16.h>
#include <math.h>

#define NN 50000
#define EE 800000
#define INCH 512
#define C1 256     // H1*HID
#define NC 16
#define NEG 0.2f

typedef __attribute__((ext_vector_type(8))) short bf16x8;
typedef __attribute__((ext_vector_type(4))) float f32x4;

__device__ inline void atomAddF(float* p, float v) {
    __hip_atomic_fetch_add(p, v, __ATOMIC_RELAXED, __HIP_MEMORY_SCOPE_AGENT);
}

__device__ inline short f2bf(float f) {
    __hip_bfloat16 h = __float2bfloat16(f);
    return *reinterpret_cast<short*>(&h);
}

// ---------------- W1 transpose + bf16 convert: W1[512,256] f32 -> W1t[256,512] bf16 ----------------
__global__ __launch_bounds__(256) void k_w1t(const float* __restrict__ W1,
                                             __hip_bfloat16* __restrict__ W1t) {
    __shared__ float t[32][33];
    int k0 = blockIdx.x * 32, n0 = blockIdx.y * 32;
    int tx = threadIdx.x & 31, ty = threadIdx.x >> 5;  // ty 0..7
#pragma unroll
    for (int i = 0; i < 4; i++) {
        t[ty + i * 8][tx] = W1[(size_t)(k0 + ty + i * 8) * C1 + n0 + tx];
    }
    __syncthreads();
#pragma unroll
    for (int i = 0; i < 4; i++) {
        W1t[(size_t)(n0 + ty + i * 8) * INCH + k0 + tx] = __float2bfloat16(t[tx][ty + i * 8]);
    }
}

// ---------------- GEMM1 (bf16 MFMA, split-x): h1 = x @ W1, fused att logits ----------------
#define BM 128
#define BN 128
#define BK 32
#define LDT 40   // bf16 row stride (32 + 8 pad): 80B = 5x16B, b128-aligned, 2-way-only conflicts
__global__ __launch_bounds__(256) void k_gemm1(const float* __restrict__ x,
                                               const __hip_bfloat16* __restrict__ W1t,
                                               const float* __restrict__ as1,
                                               const float* __restrict__ ad1,
                                               float* __restrict__ h1,
                                               float* __restrict__ a_src,
                                               float* __restrict__ a_dst) {
    __shared__ __align__(16) short Ah[BM * LDT];
    __shared__ __align__(16) short Al[BM * LDT];
    __shared__ __align__(16) short Bl[BN * LDT];
    int tid = threadIdx.x;
    int wave = tid >> 6, lane = tid & 63;
    int quad = lane >> 4, l16 = lane & 15;
    int wm = wave >> 1, wn = wave & 1;
    int bm = blockIdx.x * BM;
    int bn = blockIdx.y * BN;

    f32x4 acc[4][4];
#pragma unroll
    for (int i = 0; i < 4; i++)
#pragma unroll
        for (int j = 0; j < 4; j++) acc[i][j] = (f32x4){0.f, 0.f, 0.f, 0.f};

    for (int kt = 0; kt < INCH; kt += BK) {
        // stage A (x tile 128x32 f32 -> hi/lo bf16)
#pragma unroll
        for (int i = 0; i < 4; i++) {
            int idx = tid + 256 * i;        // float4 units, 0..1023
            int row = idx >> 3, c4 = idx & 7;
            int m = bm + row; if (m >= NN) m = NN - 1;
            float4 v = *(const float4*)&x[(size_t)m * INCH + kt + c4 * 4];
            uint ux = __float_as_uint(v.x), uy = __float_as_uint(v.y);
            uint uz = __float_as_uint(v.z), uw = __float_as_uint(v.w);
            short4 h4 = make_short4((short)(ux >> 16), (short)(uy >> 16),
                                    (short)(uz >> 16), (short)(uw >> 16));
            float4 fh = make_float4(__uint_as_float(ux & 0xFFFF0000u), __uint_as_float(uy & 0xFFFF0000u),
                                    __uint_as_float(uz & 0xFFFF0000u), __uint_as_float(uw & 0xFFFF0000u));
            short4 l4 = make_short4(f2bf(v.x - fh.x), f2bf(v.y - fh.y),
                                    f2bf(v.z - fh.z), f2bf(v.w - fh.w));
            *(short4*)&Ah[row * LDT + c4 * 4] = h4;
            *(short4*)&Al[row * LDT + c4 * 4] = l4;
        }
        // stage B (W1t tile 128x32 bf16, already converted)
#pragma unroll
        for (int i = 0; i < 2; i++) {
            int idx = tid + 256 * i;        // 8-bf16 units, 0..511
            int row = idx >> 2, c8 = idx & 3;
            float4 v = *(const float4*)(W1t + (size_t)(bn + row) * INCH + kt + c8 * 8);
            *(float4*)&Bl[row * LDT + c8 * 8] = v;
        }
        __syncthreads();
        bf16x8 afh[4], afl[4], bfr[4];
#pragma unroll
        for (int mi = 0; mi < 4; mi++) {
            afh[mi] = *(bf16x8*)&Ah[(wm * 64 + mi * 16 + l16) * LDT + quad * 8];
            afl[mi] = *(bf16x8*)&Al[(wm * 64 + mi * 16 + l16) * LDT + quad * 8];
        }
#pragma unroll
        for (int ni = 0; ni < 4; ni++)
            bfr[ni] = *(bf16x8*)&Bl[(wn * 64 + ni * 16 + l16) * LDT + quad * 8];
#pragma unroll
        for (int mi = 0; mi < 4; mi++)
#pragma unroll
            for (int ni = 0; ni < 4; ni++) {
                acc[mi][ni] = __builtin_amdgcn_mfma_f32_16x16x32_bf16(afl[mi], bfr[ni], acc[mi][ni], 0, 0, 0);
                acc[mi][ni] = __builtin_amdgcn_mfma_f32_16x16x32_bf16(afh[mi], bfr[ni], acc[mi][ni], 0, 0, 0);
            }
        __syncthreads();
    }
    // store h1 (C/D layout: col=l16, row=quad*4+r)
#pragma unroll
    for (int mi = 0; mi < 4; mi++) {
        int rowb = bm + wm * 64 + mi * 16 + quad * 4;
#pragma unroll
        for (int r = 0; r < 4; r++) {
            int gm = rowb + r;
            if (gm < NN) {
#pragma unroll
                for (int ni = 0; ni < 4; ni++)
                    h1[(size_t)gm * C1 + bn + wn * 64 + ni * 16 + l16] = acc[mi][ni][r];
            }
        }
    }
    // fused attention logits: this wave's 64 cols == one head
    int head = blockIdx.y * 2 + wn;
    float aw[4], dw[4];
#pragma unroll
    for (int ni = 0; ni < 4; ni++) {
        aw[ni] = as1[head * 64 + ni * 16 + l16];
        dw[ni] = ad1[head * 64 + ni * 16 + l16];
    }
#pragma unroll
    for (int mi = 0; mi < 4; mi++) {
#pragma unroll
        for (int r = 0; r < 4; r++) {
            float ps = acc[mi][0][r] * aw[0] + acc[mi][1][r] * aw[1] + acc[mi][2][r] * aw[2] + acc[mi][3][r] * aw[3];
            float pd = acc[mi][0][r] * dw[0] + acc[mi][1][r] * dw[1] + acc[mi][2][r] * dw[2] + acc[mi][3][r] * dw[3];
#pragma unroll
            for (int off = 8; off; off >>= 1) {
                ps += __shfl_xor(ps, off, 16);
                pd += __shfl_xor(pd, off, 16);
            }
            if (l16 == 0) {
                int gm = bm + wm * 64 + mi * 16 + quad * 4 + r;
                if (gm < NN) {
                    a_src[gm * 4 + head] = ps;
                    a_dst[gm * 4 + head] = pd;
                }
            }
        }
    }
}

// ---------------- edge exp-logits + denom + degree histogram (layer 1) ----------------
__global__ __launch_bounds__(256) void k_edge1(const int* __restrict__ esrc, const int* __restrict__ edst,
                                               const float* __restrict__ a_src, const float* __restrict__ a_dst,
                                               float* __restrict__ exnum, float* __restrict__ self1,
                                               float* __restrict__ esum, int* __restrict__ cnt) {
    int i = blockIdx.x * 256 + threadIdx.x;
    if (i >= EE + NN) return;
    int s, d;
    if (i < EE) { s = esrc[i]; d = edst[i]; } else { s = i - EE; d = s; }
    float4 vs = *(const float4*)&a_src[s * 4];
    float4 vd = *(const float4*)&a_dst[d * 4];
    float e0 = vs.x + vd.x, e1 = vs.y + vd.y, e2 = vs.z + vd.z, e3 = vs.w + vd.w;
    e0 = e0 >= 0.f ? e0 : NEG * e0;
    e1 = e1 >= 0.f ? e1 : NEG * e1;
    e2 = e2 >= 0.f ? e2 : NEG * e2;
    e3 = e3 >= 0.f ? e3 : NEG * e3;
    float x0 = __expf(e0), x1 = __expf(e1), x2 = __expf(e2), x3 = __expf(e3);
    if (i < EE) *(float4*)&exnum[(size_t)i * 4] = make_float4(x0, x1, x2, x3);
    else        *(float4*)&self1[(size_t)(i - EE) * 4] = make_float4(x0, x1, x2, x3);
    atomAddF(&esum[d * 4 + 0], x0);
    atomAddF(&esum[d * 4 + 1], x1);
    atomAddF(&esum[d * 4 + 2], x2);
    atomAddF(&esum[d * 4 + 3], x3);
    if (i < EE) atomicAdd(&cnt[d], 1);
}

// ---------------- scan (3-phase exclusive prefix over cnt[50000]) ----------------
__global__ __launch_bounds__(256) void k_scan1(const int* __restrict__ cnt, int* __restrict__ partial) {
    __shared__ int s[256];
    int i = blockIdx.x * 256 + threadIdx.x;
    s[threadIdx.x] = (i < NN) ? cnt[i] : 0;
    __syncthreads();
    for (int off = 128; off; off >>= 1) {
        if (threadIdx.x < off) s[threadIdx.x] += s[threadIdx.x + off];
        __syncthreads();
    }
    if (threadIdx.x == 0) partial[blockIdx.x] = s[0];
}

__global__ __launch_bounds__(256) void k_scan2(int* partial, int nb) {
    __shared__ int s[256];
    int t = threadIdx.x;
    int v = (t < nb) ? partial[t] : 0;
    s[t] = v;
    __syncthreads();
    for (int off = 1; off < 256; off <<= 1) {
        int y = (t >= off) ? s[t - off] : 0;
        __syncthreads();
        s[t] += y;
        __syncthreads();
    }
    if (t < nb) partial[t] = s[t] - v;  // exclusive
}

__global__ __launch_bounds__(256) void k_scan3(const int* __restrict__ cnt, const int* __restrict__ partial,
                                               int* __restrict__ row_off, int* __restrict__ cursor) {
    __shared__ int s[256];
    int t = threadIdx.x;
    int i = blockIdx.x * 256 + t;
    int v = (i < NN) ? cnt[i] : 0;
    s[t] = v;
    __syncthreads();
    for (int off = 1; off < 256; off <<= 1) {
        int y = (t >= off) ? s[t - off] : 0;
        __syncthreads();
        s[t] += y;
        __syncthreads();
    }
    if (i < NN) {
        int o = partial[blockIdx.x] + s[t] - v;
        row_off[i] = o;
        cursor[i] = o;
    }
}

// ---------------- CSR placement ----------------
__global__ __launch_bounds__(256) void k_place(const int* __restrict__ edst, int* __restrict__ cursor,
                                               int* __restrict__ csr) {
    int e = blockIdx.x * 256 + threadIdx.x;
    if (e >= EE) return;
    int d = edst[e];
    int pos = atomicAdd(&cursor[d], 1);
    csr[pos] = e;
}

// ---------------- layer-1 aggregation + bias + ELU (4-wide unrolled MLP) ----------------
__global__ __launch_bounds__(256) void k_agg1(const float* __restrict__ h1,
                                              const int* __restrict__ esrc, const int* __restrict__ csr,
                                              const int* __restrict__ row_off, const int* __restrict__ cnt,
                                              const float* __restrict__ exnum, const float* __restrict__ self1,
                                              const float* __restrict__ esum,
                                              const float* __restrict__ b1, float* __restrict__ h2in) {
    int n = blockIdx.x;
    int c = threadIdx.x;
    int h = c >> 6;
    float inv = 1.f / esum[n * 4 + h];
    float acc = self1[(size_t)n * 4 + h] * h1[(size_t)n * C1 + c];
    int base = row_off[n], deg = cnt[n];
    int k = 0;
    for (; k + 4 <= deg; k += 4) {
        int e0 = csr[base + k + 0], e1 = csr[base + k + 1], e2 = csr[base + k + 2], e3 = csr[base + k + 3];
        int s0 = esrc[e0], s1 = esrc[e1], s2 = esrc[e2], s3 = esrc[e3];
        float w0 = exnum[(size_t)e0 * 4 + h], w1 = exnum[(size_t)e1 * 4 + h];
        float w2 = exnum[(size_t)e2 * 4 + h], w3 = exnum[(size_t)e3 * 4 + h];
        float v0 = h1[(size_t)s0 * C1 + c], v1 = h1[(size_t)s1 * C1 + c];
        float v2 = h1[(size_t)s2 * C1 + c], v3 = h1[(size_t)s3 * C1 + c];
        acc += w0 * v0;
        acc += w1 * v1;
        acc += w2 * v2;
        acc += w3 * v3;
    }
    for (; k < deg; k++) {
        int e0 = csr[base + k];
        int s0 = esrc[e0];
        acc += exnum[(size_t)e0 * 4 + h] * h1[(size_t)s0 * C1 + c];
    }
    float val = acc * inv + b1[c];
    h2in[(size_t)n * C1 + c] = val > 0.f ? val : expm1f(val);
}

// ---------------- GEMM2 + layer-2 attention logits ----------------
#define LDB 260
__global__ __launch_bounds__(256) void k_gemm2(const float* __restrict__ h2in,
                                               const float* __restrict__ W2,
                                               const float* __restrict__ as2, const float* __restrict__ ad2,
                                               float* __restrict__ h2,
                                               float* __restrict__ a_src2, float* __restrict__ a_dst2) {
    __shared__ __align__(16) float ws_t[16 * LDB];  // [col][k]
    __shared__ __align__(16) float hs[16 * LDB];    // [r][k]
    int tid = threadIdx.x;
#pragma unroll
    for (int i = 0; i < 16; i++) {
        int idx = i * 256 + tid;
        int k = idx >> 4, col = idx & 15;
        ws_t[col * LDB + k] = W2[idx];
    }
    int nb = blockIdx.x * 16;
    for (int i = 0; i < 16; i++) {
        int n = nb + i;
        hs[i * LDB + tid] = (n < NN) ? h2in[(size_t)n * C1 + tid] : 0.f;
    }
    __syncthreads();
    int r = tid >> 4, col = tid & 15;
    float acc = 0.f;
    for (int k = 0; k < 256; k += 4) {
        float4 hv = *(const float4*)&hs[r * LDB + k];
        float4 wv = *(const float4*)&ws_t[col * LDB + k];
        acc += hv.x * wv.x + hv.y * wv.y + hv.z * wv.z + hv.w * wv.w;
    }
    float pa = acc * as2[col], pb = acc * ad2[col];
#pragma unroll
    for (int off = 8; off; off >>= 1) {
        pa += __shfl_xor(pa, off, 16);
        pb += __shfl_xor(pb, off, 16);
    }
    int n = nb + r;
    if (n < NN) {
        h2[(size_t)n * NC + col] = acc;
        if (col == 0) { a_src2[n] = pa; a_dst2[n] = pb; }
    }
}

// ---------------- edge exp-logits + denom (layer 2, 1 head) ----------------
__global__ __launch_bounds__(256) void k_edge2(const int* __restrict__ esrc, const int* __restrict__ edst,
                                               const float* __restrict__ a_src, const float* __restrict__ a_dst,
                                               float* __restrict__ exnum, float* __restrict__ self2,
                                               float* __restrict__ esum) {
    int i = blockIdx.x * 256 + threadIdx.x;
    if (i >= EE + NN) return;
    int s, d;
    if (i < EE) { s = esrc[i]; d = edst[i]; } else { s = i - EE; d = s; }
    float e = a_src[s] + a_dst[d];
    e = e >= 0.f ? e : NEG * e;
    float x = __expf(e);
    if (i < EE) exnum[i] = x;
    else        self2[i - EE] = x;
    atomAddF(&esum[d], x);
}

// ---------------- layer-2 aggregation + bias -> out (4-wide unrolled) ----------------
__global__ __launch_bounds__(256) void k_agg2(const float* __restrict__ h2,
                                              const int* __restrict__ esrc, const int* __restrict__ csr,
                                              const int* __restrict__ row_off, const int* __restrict__ cnt,
                                              const float* __restrict__ exnum, const float* __restrict__ self2,
                                              const float* __restrict__ esum,
                                              const float* __restrict__ b2, float* __restrict__ out) {
    int tid = threadIdx.x;
    int r = tid >> 4, col = tid & 15;
    int n = blockIdx.x * 16 + r;
    if (n >= NN) return;
    float inv = 1.f / esum[n];
    float acc = self2[n] * h2[(size_t)n * NC + col];
    int base = row_off[n], deg = cnt[n];
    int k = 0;
    for (; k + 4 <= deg; k += 4) {
        int e0 = csr[base + k + 0], e1 = csr[base + k + 1], e2 = csr[base + k + 2], e3 = csr[base + k + 3];
        int s0 = esrc[e0], s1 = esrc[e1], s2 = esrc[e2], s3 = esrc[e3];
        float w0 = exnum[e0], w1 = exnum[e1], w2 = exnum[e2], w3 = exnum[e3];
        float v0 = h2[(size_t)s0 * NC + col], v1 = h2[(size_t)s1 * NC + col];
        float v2 = h2[(size_t)s2 * NC + col], v3 = h2[(size_t)s3 * NC + col];
        acc += w0 * v0;
        acc += w1 * v1;
        acc += w2 * v2;
        acc += w3 * v3;
    }
    for (; k < deg; k++) {
        int e0 = csr[base + k];
        acc += exnum[e0] * h2[(size_t)esrc[e0] * NC + col];
    }
    out[(size_t)n * NC + col] = acc * inv + b2[col];
}

extern "C" void kernel_launch(void* const* d_in, const int* in_sizes, int n_in,
                              void* d_out, int out_size, void* d_ws, size_t ws_size,
                              hipStream_t stream) {
    const float* x   = (const float*)d_in[0];
    const int*   ei  = (const int*)d_in[1];
    const int*   esrc = ei;
    const int*   edst = ei + EE;
    const float* W1  = (const float*)d_in[2];
    const float* as1 = (const float*)d_in[3];
    const float* ad1 = (const float*)d_in[4];
    const float* b1  = (const float*)d_in[5];
    const float* W2  = (const float*)d_in[6];
    const float* as2 = (const float*)d_in[7];
    const float* ad2 = (const float*)d_in[8];
    const float* b2  = (const float*)d_in[9];
    float* out = (float*)d_out;

    char* w = (char*)d_ws;
    size_t off = 0;
    auto alloc = [&](size_t bytes) -> void* {
        void* p = w + off;
        off += (bytes + 255) & ~(size_t)255;
        return p;
    };
    float* h1     = (float*)alloc((size_t)NN * C1 * 4);
    float* h2in   = (float*)alloc((size_t)NN * C1 * 4);
    float* exnum1 = (float*)alloc((size_t)EE * 4 * 4);
    float* self1  = (float*)alloc((size_t)NN * 4 * 4);
    int*   csr    = (int*)alloc((size_t)EE * 4);
    float* exnum2 = (float*)alloc((size_t)EE * 4);
    float* self2  = (float*)alloc((size_t)NN * 4);
    float* h2     = (float*)alloc((size_t)NN * NC * 4);
    float* a_src1 = (float*)alloc((size_t)NN * 4 * 4);
    float* a_dst1 = (float*)alloc((size_t)NN * 4 * 4);
    float* esum1  = (float*)alloc((size_t)NN * 4 * 4);
    int*   cnt    = (int*)alloc((size_t)NN * 4);
    int*   row_off= (int*)alloc((size_t)NN * 4);
    int*   cursor = (int*)alloc((size_t)NN * 4);
    float* a_src2 = (float*)alloc((size_t)NN * 4);
    float* a_dst2 = (float*)alloc((size_t)NN * 4);
    float* esum2  = (float*)alloc((size_t)NN * 4);
    int*   partial= (int*)alloc(256 * 4);
    __hip_bfloat16* W1t = (__hip_bfloat16*)alloc((size_t)C1 * INCH * 2);

    hipMemsetAsync(esum1, 0, (size_t)NN * 4 * 4, stream);
    hipMemsetAsync(cnt, 0, (size_t)NN * 4, stream);
    hipMemsetAsync(esum2, 0, (size_t)NN * 4, stream);

    const int NBLK = (NN + 255) / 256;          // 196
    const int EBLK = (EE + NN + 255) / 256;     // 3321

    k_w1t<<<dim3(INCH / 32, C1 / 32), 256, 0, stream>>>(W1, W1t);
    dim3 g1((NN + BM - 1) / BM, C1 / BN);       // (391, 2)
    k_gemm1<<<g1, 256, 0, stream>>>(x, W1t, as1, ad1, h1, a_src1, a_dst1);
    k_edge1<<<EBLK, 256, 0, stream>>>(esrc, edst, a_src1, a_dst1, exnum1, self1, esum1, cnt);
    k_scan1<<<NBLK, 256, 0, stream>>>(cnt, partial);
    k_scan2<<<1, 256, 0, stream>>>(partial, NBLK);
    k_scan3<<<NBLK, 256, 0, stream>>>(cnt, partial, row_off, cursor);
    k_place<<<(EE + 255) / 256, 256, 0, stream>>>(edst, cursor, csr);
    k_agg1<<<NN, 256, 0, stream>>>(h1, esrc, csr, row_off, cnt, exnum1, self1, esum1, b1, h2in);
    k_gemm2<<<(NN + 15) / 16, 256, 0, stream>>>(h2in, W2, as2, ad2, h2, a_src2, a_dst2);
    k_edge2<<<EBLK, 256, 0, stream>>>(esrc, edst, a_src2, a_dst2, exnum2, self2, esum2);
    k_agg2<<<(NN + 15) / 16, 256, 0, stream>>>(h2, esrc, csr, row_off, cnt, exnum2, self2, esum2, b2, out);
}

// Round 4
// 467.190 us; speedup vs baseline: 2.2342x; 1.6418x over previous
//
#include <hip/hip_runtime.h>
#include <hip/hip_bf16.h>
#include <math.h>

#define NN 50000
#define EE 800000
#define INCH 512
#define C1 256     // H1*HID
#define NC 16
#define NEG 0.2f

typedef __attribute__((ext_vector_type(8))) short bf16x8;
typedef __attribute__((ext_vector_type(4))) float f32x4;

__device__ inline short f2bf(float f) {
    __hip_bfloat16 h = __float2bfloat16(f);
    return *reinterpret_cast<short*>(&h);
}

// ---------------- W1 transpose + bf16 convert: W1[512,256] f32 -> W1t[256,512] bf16 ----------------
__global__ __launch_bounds__(256) void k_w1t(const float* __restrict__ W1,
                                             __hip_bfloat16* __restrict__ W1t) {
    __shared__ float t[32][33];
    int k0 = blockIdx.x * 32, n0 = blockIdx.y * 32;
    int tx = threadIdx.x & 31, ty = threadIdx.x >> 5;  // ty 0..7
#pragma unroll
    for (int i = 0; i < 4; i++) {
        t[ty + i * 8][tx] = W1[(size_t)(k0 + ty + i * 8) * C1 + n0 + tx];
    }
    __syncthreads();
#pragma unroll
    for (int i = 0; i < 4; i++) {
        W1t[(size_t)(n0 + ty + i * 8) * INCH + k0 + tx] = __float2bfloat16(t[tx][ty + i * 8]);
    }
}

// ---------------- GEMM1 (bf16 MFMA, split-x): h1 = x @ W1, fused att logits ----------------
#define BM 128
#define BN 128
#define BK 32
#define LDT 40   // bf16 row stride (32 + 8 pad)
__global__ __launch_bounds__(256) void k_gemm1(const float* __restrict__ x,
                                               const __hip_bfloat16* __restrict__ W1t,
                                               const float* __restrict__ as1,
                                               const float* __restrict__ ad1,
                                               float* __restrict__ h1,
                                               float* __restrict__ a_src,
                                               float* __restrict__ a_dst) {
    __shared__ __align__(16) short Ah[BM * LDT];
    __shared__ __align__(16) short Al[BM * LDT];
    __shared__ __align__(16) short Bl[BN * LDT];
    int tid = threadIdx.x;
    int wave = tid >> 6, lane = tid & 63;
    int quad = lane >> 4, l16 = lane & 15;
    int wm = wave >> 1, wn = wave & 1;
    int bm = blockIdx.x * BM;
    int bn = blockIdx.y * BN;

    f32x4 acc[4][4];
#pragma unroll
    for (int i = 0; i < 4; i++)
#pragma unroll
        for (int j = 0; j < 4; j++) acc[i][j] = (f32x4){0.f, 0.f, 0.f, 0.f};

    for (int kt = 0; kt < INCH; kt += BK) {
        // stage A (x tile 128x32 f32 -> hi/lo bf16)
#pragma unroll
        for (int i = 0; i < 4; i++) {
            int idx = tid + 256 * i;        // float4 units, 0..1023
            int row = idx >> 3, c4 = idx & 7;
            int m = bm + row; if (m >= NN) m = NN - 1;
            float4 v = *(const float4*)&x[(size_t)m * INCH + kt + c4 * 4];
            uint ux = __float_as_uint(v.x), uy = __float_as_uint(v.y);
            uint uz = __float_as_uint(v.z), uw = __float_as_uint(v.w);
            short4 h4 = make_short4((short)(ux >> 16), (short)(uy >> 16),
                                    (short)(uz >> 16), (short)(uw >> 16));
            float4 fh = make_float4(__uint_as_float(ux & 0xFFFF0000u), __uint_as_float(uy & 0xFFFF0000u),
                                    __uint_as_float(uz & 0xFFFF0000u), __uint_as_float(uw & 0xFFFF0000u));
            short4 l4 = make_short4(f2bf(v.x - fh.x), f2bf(v.y - fh.y),
                                    f2bf(v.z - fh.z), f2bf(v.w - fh.w));
            *(short4*)&Ah[row * LDT + c4 * 4] = h4;
            *(short4*)&Al[row * LDT + c4 * 4] = l4;
        }
        // stage B (W1t tile 128x32 bf16, already converted)
#pragma unroll
        for (int i = 0; i < 2; i++) {
            int idx = tid + 256 * i;        // 8-bf16 units, 0..511
            int row = idx >> 2, c8 = idx & 3;
            float4 v = *(const float4*)(W1t + (size_t)(bn + row) * INCH + kt + c8 * 8);
            *(float4*)&Bl[row * LDT + c8 * 8] = v;
        }
        __syncthreads();
        bf16x8 afh[4], afl[4], bfr[4];
#pragma unroll
        for (int mi = 0; mi < 4; mi++) {
            afh[mi] = *(bf16x8*)&Ah[(wm * 64 + mi * 16 + l16) * LDT + quad * 8];
            afl[mi] = *(bf16x8*)&Al[(wm * 64 + mi * 16 + l16) * LDT + quad * 8];
        }
#pragma unroll
        for (int ni = 0; ni < 4; ni++)
            bfr[ni] = *(bf16x8*)&Bl[(wn * 64 + ni * 16 + l16) * LDT + quad * 8];
#pragma unroll
        for (int mi = 0; mi < 4; mi++)
#pragma unroll
            for (int ni = 0; ni < 4; ni++) {
                acc[mi][ni] = __builtin_amdgcn_mfma_f32_16x16x32_bf16(afl[mi], bfr[ni], acc[mi][ni], 0, 0, 0);
                acc[mi][ni] = __builtin_amdgcn_mfma_f32_16x16x32_bf16(afh[mi], bfr[ni], acc[mi][ni], 0, 0, 0);
            }
        __syncthreads();
    }
    // store h1 (C/D layout: col=l16, row=quad*4+r)
#pragma unroll
    for (int mi = 0; mi < 4; mi++) {
        int rowb = bm + wm * 64 + mi * 16 + quad * 4;
#pragma unroll
        for (int r = 0; r < 4; r++) {
            int gm = rowb + r;
            if (gm < NN) {
#pragma unroll
                for (int ni = 0; ni < 4; ni++)
                    h1[(size_t)gm * C1 + bn + wn * 64 + ni * 16 + l16] = acc[mi][ni][r];
            }
        }
    }
    // fused attention logits: this wave's 64 cols == one head
    int head = blockIdx.y * 2 + wn;
    float aw[4], dw[4];
#pragma unroll
    for (int ni = 0; ni < 4; ni++) {
        aw[ni] = as1[head * 64 + ni * 16 + l16];
        dw[ni] = ad1[head * 64 + ni * 16 + l16];
    }
#pragma unroll
    for (int mi = 0; mi < 4; mi++) {
#pragma unroll
        for (int r = 0; r < 4; r++) {
            float ps = acc[mi][0][r] * aw[0] + acc[mi][1][r] * aw[1] + acc[mi][2][r] * aw[2] + acc[mi][3][r] * aw[3];
            float pd = acc[mi][0][r] * dw[0] + acc[mi][1][r] * dw[1] + acc[mi][2][r] * dw[2] + acc[mi][3][r] * dw[3];
#pragma unroll
            for (int off = 8; off; off >>= 1) {
                ps += __shfl_xor(ps, off, 16);
                pd += __shfl_xor(pd, off, 16);
            }
            if (l16 == 0) {
                int gm = bm + wm * 64 + mi * 16 + quad * 4 + r;
                if (gm < NN) {
                    a_src[gm * 4 + head] = ps;
                    a_dst[gm * 4 + head] = pd;
                }
            }
        }
    }
}

// ---------------- degree histogram ----------------
__global__ __launch_bounds__(256) void k_hist(const int* __restrict__ edst, int* __restrict__ cnt) {
    int e = blockIdx.x * 256 + threadIdx.x;
    if (e < EE) atomicAdd(&cnt[edst[e]], 1);
}

// ---------------- scan (3-phase exclusive prefix over cnt[50000]) ----------------
__global__ __launch_bounds__(256) void k_scan1(const int* __restrict__ cnt, int* __restrict__ partial) {
    __shared__ int s[256];
    int i = blockIdx.x * 256 + threadIdx.x;
    s[threadIdx.x] = (i < NN) ? cnt[i] : 0;
    __syncthreads();
    for (int off = 128; off; off >>= 1) {
        if (threadIdx.x < off) s[threadIdx.x] += s[threadIdx.x + off];
        __syncthreads();
    }
    if (threadIdx.x == 0) partial[blockIdx.x] = s[0];
}

__global__ __launch_bounds__(256) void k_scan2(int* partial, int nb) {
    __shared__ int s[256];
    int t = threadIdx.x;
    int v = (t < nb) ? partial[t] : 0;
    s[t] = v;
    __syncthreads();
    for (int off = 1; off < 256; off <<= 1) {
        int y = (t >= off) ? s[t - off] : 0;
        __syncthreads();
        s[t] += y;
        __syncthreads();
    }
    if (t < nb) partial[t] = s[t] - v;  // exclusive
}

__global__ __launch_bounds__(256) void k_scan3(const int* __restrict__ cnt, const int* __restrict__ partial,
                                               int* __restrict__ row_off, int* __restrict__ cursor) {
    __shared__ int s[256];
    int t = threadIdx.x;
    int i = blockIdx.x * 256 + t;
    int v = (i < NN) ? cnt[i] : 0;
    s[t] = v;
    __syncthreads();
    for (int off = 1; off < 256; off <<= 1) {
        int y = (t >= off) ? s[t - off] : 0;
        __syncthreads();
        s[t] += y;
        __syncthreads();
    }
    if (i < NN) {
        int o = partial[blockIdx.x] + s[t] - v;
        row_off[i] = o;
        cursor[i] = o;
    }
}

// ---------------- CSR placement (stores SRC node id directly) ----------------
__global__ __launch_bounds__(256) void k_place(const int* __restrict__ esrc, const int* __restrict__ edst,
                                               int* __restrict__ cursor, int* __restrict__ csr) {
    int e = blockIdx.x * 256 + threadIdx.x;
    if (e >= EE) return;
    int d = edst[e];
    int s = esrc[e];
    int pos = atomicAdd(&cursor[d], 1);
    csr[pos] = s;
}

// ---------------- layer-1 aggregation: fused softmax + gather + bias + ELU ----------------
__global__ __launch_bounds__(256) void k_agg1(const float* __restrict__ h1,
                                              const int* __restrict__ csr,
                                              const int* __restrict__ row_off, const int* __restrict__ cnt,
                                              const float* __restrict__ a_src, const float* __restrict__ a_dst,
                                              const float* __restrict__ b1, float* __restrict__ h2in) {
    int n = blockIdx.x;
    int c = threadIdx.x;
    int h = c >> 6;
    float adn = a_dst[n * 4 + h];
    // self loop
    float es = a_src[n * 4 + h] + adn;
    es = es >= 0.f ? es : NEG * es;
    float wse = __expf(es);
    float denom = wse;
    float acc = wse * h1[(size_t)n * C1 + c];
    int base = row_off[n], deg = cnt[n];
    int k = 0;
    for (; k + 4 <= deg; k += 4) {
        int s0 = csr[base + k + 0], s1 = csr[base + k + 1];
        int s2 = csr[base + k + 2], s3 = csr[base + k + 3];
        float e0 = a_src[s0 * 4 + h] + adn, e1 = a_src[s1 * 4 + h] + adn;
        float e2 = a_src[s2 * 4 + h] + adn, e3 = a_src[s3 * 4 + h] + adn;
        float v0 = h1[(size_t)s0 * C1 + c], v1 = h1[(size_t)s1 * C1 + c];
        float v2 = h1[(size_t)s2 * C1 + c], v3 = h1[(size_t)s3 * C1 + c];
        e0 = e0 >= 0.f ? e0 : NEG * e0;
        e1 = e1 >= 0.f ? e1 : NEG * e1;
        e2 = e2 >= 0.f ? e2 : NEG * e2;
        e3 = e3 >= 0.f ? e3 : NEG * e3;
        float w0 = __expf(e0), w1 = __expf(e1), w2 = __expf(e2), w3 = __expf(e3);
        denom += w0; acc += w0 * v0;
        denom += w1; acc += w1 * v1;
        denom += w2; acc += w2 * v2;
        denom += w3; acc += w3 * v3;
    }
    for (; k < deg; k++) {
        int s0 = csr[base + k];
        float e0 = a_src[s0 * 4 + h] + adn;
        e0 = e0 >= 0.f ? e0 : NEG * e0;
        float w0 = __expf(e0);
        denom += w0;
        acc += w0 * h1[(size_t)s0 * C1 + c];
    }
    float val = acc / denom + b1[c];
    h2in[(size_t)n * C1 + c] = val > 0.f ? val : expm1f(val);
}

// ---------------- GEMM2 + layer-2 attention logits ----------------
#define LDB 260
__global__ __launch_bounds__(256) void k_gemm2(const float* __restrict__ h2in,
                                               const float* __restrict__ W2,
                                               const float* __restrict__ as2, const float* __restrict__ ad2,
                                               float* __restrict__ h2,
                                               float* __restrict__ a_src2, float* __restrict__ a_dst2) {
    __shared__ __align__(16) float ws_t[16 * LDB];  // [col][k]
    __shared__ __align__(16) float hs[16 * LDB];    // [r][k]
    int tid = threadIdx.x;
#pragma unroll
    for (int i = 0; i < 16; i++) {
        int idx = i * 256 + tid;
        int k = idx >> 4, col = idx & 15;
        ws_t[col * LDB + k] = W2[idx];
    }
    int nb = blockIdx.x * 16;
    for (int i = 0; i < 16; i++) {
        int n = nb + i;
        hs[i * LDB + tid] = (n < NN) ? h2in[(size_t)n * C1 + tid] : 0.f;
    }
    __syncthreads();
    int r = tid >> 4, col = tid & 15;
    float acc = 0.f;
    for (int k = 0; k < 256; k += 4) {
        float4 hv = *(const float4*)&hs[r * LDB + k];
        float4 wv = *(const float4*)&ws_t[col * LDB + k];
        acc += hv.x * wv.x + hv.y * wv.y + hv.z * wv.z + hv.w * wv.w;
    }
    float pa = acc * as2[col], pb = acc * ad2[col];
#pragma unroll
    for (int off = 8; off; off >>= 1) {
        pa += __shfl_xor(pa, off, 16);
        pb += __shfl_xor(pb, off, 16);
    }
    int n = nb + r;
    if (n < NN) {
        h2[(size_t)n * NC + col] = acc;
        if (col == 0) { a_src2[n] = pa; a_dst2[n] = pb; }
    }
}

// ---------------- layer-2 aggregation: fused softmax + gather + bias -> out ----------------
__global__ __launch_bounds__(256) void k_agg2(const float* __restrict__ h2,
                                              const int* __restrict__ csr,
                                              const int* __restrict__ row_off, const int* __restrict__ cnt,
                                              const float* __restrict__ a_src2, const float* __restrict__ a_dst2,
                                              const float* __restrict__ b2, float* __restrict__ out) {
    int tid = threadIdx.x;
    int r = tid >> 4, col = tid & 15;
    int n = blockIdx.x * 16 + r;
    if (n >= NN) return;
    float adn = a_dst2[n];
    float es = a_src2[n] + adn;
    es = es >= 0.f ? es : NEG * es;
    float wse = __expf(es);
    float denom = wse;
    float acc = wse * h2[(size_t)n * NC + col];
    int base = row_off[n], deg = cnt[n];
    int k = 0;
    for (; k + 4 <= deg; k += 4) {
        int s0 = csr[base + k + 0], s1 = csr[base + k + 1];
        int s2 = csr[base + k + 2], s3 = csr[base + k + 3];
        float e0 = a_src2[s0] + adn, e1 = a_src2[s1] + adn;
        float e2 = a_src2[s2] + adn, e3 = a_src2[s3] + adn;
        float v0 = h2[(size_t)s0 * NC + col], v1 = h2[(size_t)s1 * NC + col];
        float v2 = h2[(size_t)s2 * NC + col], v3 = h2[(size_t)s3 * NC + col];
        e0 = e0 >= 0.f ? e0 : NEG * e0;
        e1 = e1 >= 0.f ? e1 : NEG * e1;
        e2 = e2 >= 0.f ? e2 : NEG * e2;
        e3 = e3 >= 0.f ? e3 : NEG * e3;
        float w0 = __expf(e0), w1 = __expf(e1), w2 = __expf(e2), w3 = __expf(e3);
        denom += w0; acc += w0 * v0;
        denom += w1; acc += w1 * v1;
        denom += w2; acc += w2 * v2;
        denom += w3; acc += w3 * v3;
    }
    for (; k < deg; k++) {
        int s0 = csr[base + k];
        float e0 = a_src2[s0] + adn;
        e0 = e0 >= 0.f ? e0 : NEG * e0;
        float w0 = __expf(e0);
        denom += w0;
        acc += w0 * h2[(size_t)s0 * NC + col];
    }
    out[(size_t)n * NC + col] = acc / denom + b2[col];
}

extern "C" void kernel_launch(void* const* d_in, const int* in_sizes, int n_in,
                              void* d_out, int out_size, void* d_ws, size_t ws_size,
                              hipStream_t stream) {
    const float* x   = (const float*)d_in[0];
    const int*   ei  = (const int*)d_in[1];
    const int*   esrc = ei;
    const int*   edst = ei + EE;
    const float* W1  = (const float*)d_in[2];
    const float* as1 = (const float*)d_in[3];
    const float* ad1 = (const float*)d_in[4];
    const float* b1  = (const float*)d_in[5];
    const float* W2  = (const float*)d_in[6];
    const float* as2 = (const float*)d_in[7];
    const float* ad2 = (const float*)d_in[8];
    const float* b2  = (const float*)d_in[9];
    float* out = (float*)d_out;

    char* w = (char*)d_ws;
    size_t off = 0;
    auto alloc = [&](size_t bytes) -> void* {
        void* p = w + off;
        off += (bytes + 255) & ~(size_t)255;
        return p;
    };
    float* h1     = (float*)alloc((size_t)NN * C1 * 4);
    float* h2in   = (float*)alloc((size_t)NN * C1 * 4);
    int*   csr    = (int*)alloc((size_t)EE * 4);
    float* h2     = (float*)alloc((size_t)NN * NC * 4);
    float* a_src1 = (float*)alloc((size_t)NN * 4 * 4);
    float* a_dst1 = (float*)alloc((size_t)NN * 4 * 4);
    int*   cnt    = (int*)alloc((size_t)NN * 4);
    int*   row_off= (int*)alloc((size_t)NN * 4);
    int*   cursor = (int*)alloc((size_t)NN * 4);
    float* a_src2 = (float*)alloc((size_t)NN * 4);
    float* a_dst2 = (float*)alloc((size_t)NN * 4);
    int*   partial= (int*)alloc(256 * 4);
    __hip_bfloat16* W1t = (__hip_bfloat16*)alloc((size_t)C1 * INCH * 2);

    hipMemsetAsync(cnt, 0, (size_t)NN * 4, stream);

    const int NBLK = (NN + 255) / 256;          // 196
    const int EBLK = (EE + 255) / 256;          // 3125

    k_w1t<<<dim3(INCH / 32, C1 / 32), 256, 0, stream>>>(W1, W1t);
    k_hist<<<EBLK, 256, 0, stream>>>(edst, cnt);
    dim3 g1((NN + BM - 1) / BM, C1 / BN);       // (391, 2)
    k_gemm1<<<g1, 256, 0, stream>>>(x, W1t, as1, ad1, h1, a_src1, a_dst1);
    k_scan1<<<NBLK, 256, 0, stream>>>(cnt, partial);
    k_scan2<<<1, 256, 0, stream>>>(partial, NBLK);
    k_scan3<<<NBLK, 256, 0, stream>>>(cnt, partial, row_off, cursor);
    k_place<<<EBLK, 256, 0, stream>>>(esrc, edst, cursor, csr);
    k_agg1<<<NN, 256, 0, stream>>>(h1, csr, row_off, cnt, a_src1, a_dst1, b1, h2in);
    k_gemm2<<<(NN + 15) / 16, 256, 0, stream>>>(h2in, W2, as2, ad2, h2, a_src2, a_dst2);
    k_agg2<<<(NN + 15) / 16, 256, 0, stream>>>(h2, csr, row_off, cnt, a_src2, a_dst2, b2, out);
}

// Round 5
// 446.087 us; speedup vs baseline: 2.3399x; 1.0473x over previous
//
#include <hip/hip_runtime.h>
#include <hip/hip_bf16.h>
#include <math.h>

#define NN 50000
#define EE 800000
#define INCH 512
#define C1 256     // H1*HID
#define NC 16
#define NEG 0.2f

typedef __attribute__((ext_vector_type(8))) short bf16x8;
typedef __attribute__((ext_vector_type(4))) float f32x4;

__device__ inline short f2bf(float f) {
    __hip_bfloat16 h = __float2bfloat16(f);
    return *reinterpret_cast<short*>(&h);
}

__device__ inline float bfu2f(unsigned short u) {
    return __uint_as_float(((unsigned int)u) << 16);
}

// ---------------- W1 transpose + bf16 convert: W1[512,256] f32 -> W1t[256,512] bf16 ----------------
__global__ __launch_bounds__(256) void k_w1t(const float* __restrict__ W1,
                                             __hip_bfloat16* __restrict__ W1t) {
    __shared__ float t[32][33];
    int k0 = blockIdx.x * 32, n0 = blockIdx.y * 32;
    int tx = threadIdx.x & 31, ty = threadIdx.x >> 5;  // ty 0..7
#pragma unroll
    for (int i = 0; i < 4; i++) {
        t[ty + i * 8][tx] = W1[(size_t)(k0 + ty + i * 8) * C1 + n0 + tx];
    }
    __syncthreads();
#pragma unroll
    for (int i = 0; i < 4; i++) {
        W1t[(size_t)(n0 + ty + i * 8) * INCH + k0 + tx] = __float2bfloat16(t[tx][ty + i * 8]);
    }
}

// ---------------- GEMM1 (bf16 MFMA, split-x): h1(bf16) = x @ W1, fused att logits ----------------
#define BM 128
#define BN 128
#define BK 32
#define LDT 40   // bf16 row stride (32 + 8 pad)
__global__ __launch_bounds__(256) void k_gemm1(const float* __restrict__ x,
                                               const __hip_bfloat16* __restrict__ W1t,
                                               const float* __restrict__ as1,
                                               const float* __restrict__ ad1,
                                               unsigned short* __restrict__ h1b,
                                               float* __restrict__ a_src,
                                               float* __restrict__ a_dst) {
    __shared__ __align__(16) short Ah[BM * LDT];
    __shared__ __align__(16) short Al[BM * LDT];
    __shared__ __align__(16) short Bl[BN * LDT];
    int tid = threadIdx.x;
    int wave = tid >> 6, lane = tid & 63;
    int quad = lane >> 4, l16 = lane & 15;
    int wm = wave >> 1, wn = wave & 1;
    int bm = blockIdx.x * BM;
    int bn = blockIdx.y * BN;

    f32x4 acc[4][4];
#pragma unroll
    for (int i = 0; i < 4; i++)
#pragma unroll
        for (int j = 0; j < 4; j++) acc[i][j] = (f32x4){0.f, 0.f, 0.f, 0.f};

    for (int kt = 0; kt < INCH; kt += BK) {
        // stage A (x tile 128x32 f32 -> hi/lo bf16)
#pragma unroll
        for (int i = 0; i < 4; i++) {
            int idx = tid + 256 * i;        // float4 units, 0..1023
            int row = idx >> 3, c4 = idx & 7;
            int m = bm + row; if (m >= NN) m = NN - 1;
            float4 v = *(const float4*)&x[(size_t)m * INCH + kt + c4 * 4];
            uint ux = __float_as_uint(v.x), uy = __float_as_uint(v.y);
            uint uz = __float_as_uint(v.z), uw = __float_as_uint(v.w);
            short4 h4 = make_short4((short)(ux >> 16), (short)(uy >> 16),
                                    (short)(uz >> 16), (short)(uw >> 16));
            float4 fh = make_float4(__uint_as_float(ux & 0xFFFF0000u), __uint_as_float(uy & 0xFFFF0000u),
                                    __uint_as_float(uz & 0xFFFF0000u), __uint_as_float(uw & 0xFFFF0000u));
            short4 l4 = make_short4(f2bf(v.x - fh.x), f2bf(v.y - fh.y),
                                    f2bf(v.z - fh.z), f2bf(v.w - fh.w));
            *(short4*)&Ah[row * LDT + c4 * 4] = h4;
            *(short4*)&Al[row * LDT + c4 * 4] = l4;
        }
        // stage B (W1t tile 128x32 bf16, already converted)
#pragma unroll
        for (int i = 0; i < 2; i++) {
            int idx = tid + 256 * i;        // 8-bf16 units, 0..511
            int row = idx >> 2, c8 = idx & 3;
            float4 v = *(const float4*)(W1t + (size_t)(bn + row) * INCH + kt + c8 * 8);
            *(float4*)&Bl[row * LDT + c8 * 8] = v;
        }
        __syncthreads();
        bf16x8 afh[4], afl[4], bfr[4];
#pragma unroll
        for (int mi = 0; mi < 4; mi++) {
            afh[mi] = *(bf16x8*)&Ah[(wm * 64 + mi * 16 + l16) * LDT + quad * 8];
            afl[mi] = *(bf16x8*)&Al[(wm * 64 + mi * 16 + l16) * LDT + quad * 8];
        }
#pragma unroll
        for (int ni = 0; ni < 4; ni++)
            bfr[ni] = *(bf16x8*)&Bl[(wn * 64 + ni * 16 + l16) * LDT + quad * 8];
#pragma unroll
        for (int mi = 0; mi < 4; mi++)
#pragma unroll
            for (int ni = 0; ni < 4; ni++) {
                acc[mi][ni] = __builtin_amdgcn_mfma_f32_16x16x32_bf16(afl[mi], bfr[ni], acc[mi][ni], 0, 0, 0);
                acc[mi][ni] = __builtin_amdgcn_mfma_f32_16x16x32_bf16(afh[mi], bfr[ni], acc[mi][ni], 0, 0, 0);
            }
        __syncthreads();
    }
    // store h1 as bf16 (C/D layout: col=l16, row=quad*4+r)
#pragma unroll
    for (int mi = 0; mi < 4; mi++) {
        int rowb = bm + wm * 64 + mi * 16 + quad * 4;
#pragma unroll
        for (int r = 0; r < 4; r++) {
            int gm = rowb + r;
            if (gm < NN) {
#pragma unroll
                for (int ni = 0; ni < 4; ni++)
                    h1b[(size_t)gm * C1 + bn + wn * 64 + ni * 16 + l16] =
                        (unsigned short)f2bf(acc[mi][ni][r]);
            }
        }
    }
    // fused attention logits (from f32 accumulators): this wave's 64 cols == one head
    int head = blockIdx.y * 2 + wn;
    float aw[4], dw[4];
#pragma unroll
    for (int ni = 0; ni < 4; ni++) {
        aw[ni] = as1[head * 64 + ni * 16 + l16];
        dw[ni] = ad1[head * 64 + ni * 16 + l16];
    }
#pragma unroll
    for (int mi = 0; mi < 4; mi++) {
#pragma unroll
        for (int r = 0; r < 4; r++) {
            float ps = acc[mi][0][r] * aw[0] + acc[mi][1][r] * aw[1] + acc[mi][2][r] * aw[2] + acc[mi][3][r] * aw[3];
            float pd = acc[mi][0][r] * dw[0] + acc[mi][1][r] * dw[1] + acc[mi][2][r] * dw[2] + acc[mi][3][r] * dw[3];
#pragma unroll
            for (int off = 8; off; off >>= 1) {
                ps += __shfl_xor(ps, off, 16);
                pd += __shfl_xor(pd, off, 16);
            }
            if (l16 == 0) {
                int gm = bm + wm * 64 + mi * 16 + quad * 4 + r;
                if (gm < NN) {
                    a_src[gm * 4 + head] = ps;
                    a_dst[gm * 4 + head] = pd;
                }
            }
        }
    }
}

// ---------------- degree histogram ----------------
__global__ __launch_bounds__(256) void k_hist(const int* __restrict__ edst, int* __restrict__ cnt) {
    int e = blockIdx.x * 256 + threadIdx.x;
    if (e < EE) atomicAdd(&cnt[edst[e]], 1);
}

// ---------------- scan (3-phase exclusive prefix over cnt[50000]) ----------------
__global__ __launch_bounds__(256) void k_scan1(const int* __restrict__ cnt, int* __restrict__ partial) {
    __shared__ int s[256];
    int i = blockIdx.x * 256 + threadIdx.x;
    s[threadIdx.x] = (i < NN) ? cnt[i] : 0;
    __syncthreads();
    for (int off = 128; off; off >>= 1) {
        if (threadIdx.x < off) s[threadIdx.x] += s[threadIdx.x + off];
        __syncthreads();
    }
    if (threadIdx.x == 0) partial[blockIdx.x] = s[0];
}

__global__ __launch_bounds__(256) void k_scan2(int* partial, int nb) {
    __shared__ int s[256];
    int t = threadIdx.x;
    int v = (t < nb) ? partial[t] : 0;
    s[t] = v;
    __syncthreads();
    for (int off = 1; off < 256; off <<= 1) {
        int y = (t >= off) ? s[t - off] : 0;
        __syncthreads();
        s[t] += y;
        __syncthreads();
    }
    if (t < nb) partial[t] = s[t] - v;  // exclusive
}

__global__ __launch_bounds__(256) void k_scan3(const int* __restrict__ cnt, const int* __restrict__ partial,
                                               int* __restrict__ row_off, int* __restrict__ cursor) {
    __shared__ int s[256];
    int t = threadIdx.x;
    int i = blockIdx.x * 256 + t;
    int v = (i < NN) ? cnt[i] : 0;
    s[t] = v;
    __syncthreads();
    for (int off = 1; off < 256; off <<= 1) {
        int y = (t >= off) ? s[t - off] : 0;
        __syncthreads();
        s[t] += y;
        __syncthreads();
    }
    if (i < NN) {
        int o = partial[blockIdx.x] + s[t] - v;
        row_off[i] = o;
        cursor[i] = o;
    }
}

// ---------------- CSR placement (stores SRC node id directly) ----------------
__global__ __launch_bounds__(256) void k_place(const int* __restrict__ esrc, const int* __restrict__ edst,
                                               int* __restrict__ cursor, int* __restrict__ csr) {
    int e = blockIdx.x * 256 + threadIdx.x;
    if (e >= EE) return;
    int d = edst[e];
    int s = esrc[e];
    int pos = atomicAdd(&cursor[d], 1);
    csr[pos] = s;
}

// ---------------- layer-1 aggregation: LDS-staged weights + bf16 gather + bias + ELU --------
__global__ __launch_bounds__(256) void k_agg1(const unsigned short* __restrict__ h1b,
                                              const int* __restrict__ csr,
                                              const int* __restrict__ row_off, const int* __restrict__ cnt,
                                              const float* __restrict__ a_src, const float* __restrict__ a_dst,
                                              const float* __restrict__ b1, float* __restrict__ h2in) {
    __shared__ float wsh[64 * 4];
    __shared__ int ssh[64];
    int n = blockIdx.x;
    int c = threadIdx.x;
    int h = c >> 6;
    int base = row_off[n], deg = cnt[n];
    // phase-1 thread mapping: edge = tid>>2, head = tid&3
    int pe = c >> 2, ph = c & 3;
    float adnh = a_dst[n * 4 + ph];   // for phase 1 (this thread's head)
    float adn = a_dst[n * 4 + h];     // for self loop (this wave's head)

    // self loop
    float es = a_src[n * 4 + h] + adn;
    es = es >= 0.f ? es : NEG * es;
    float wse = __expf(es);
    float denom = wse;
    float acc = wse * bfu2f(h1b[(size_t)n * C1 + c]);

    for (int k0 = 0; k0 < deg; k0 += 64) {
        int kk = k0 + pe;
        if (kk < deg) {
            int s = csr[base + kk];
            if (ph == 0) ssh[pe] = s;
            float e = a_src[s * 4 + ph] + adnh;
            e = e >= 0.f ? e : NEG * e;
            wsh[pe * 4 + ph] = __expf(e);
        }
        __syncthreads();
        int m = deg - k0; if (m > 64) m = 64;
        int k = 0;
        for (; k + 4 <= m; k += 4) {
            float w0 = wsh[(k + 0) * 4 + h], w1 = wsh[(k + 1) * 4 + h];
            float w2 = wsh[(k + 2) * 4 + h], w3 = wsh[(k + 3) * 4 + h];
            int s0 = ssh[k + 0], s1 = ssh[k + 1], s2 = ssh[k + 2], s3 = ssh[k + 3];
            float v0 = bfu2f(h1b[(size_t)s0 * C1 + c]);
            float v1 = bfu2f(h1b[(size_t)s1 * C1 + c]);
            float v2 = bfu2f(h1b[(size_t)s2 * C1 + c]);
            float v3 = bfu2f(h1b[(size_t)s3 * C1 + c]);
            denom += w0; acc += w0 * v0;
            denom += w1; acc += w1 * v1;
            denom += w2; acc += w2 * v2;
            denom += w3; acc += w3 * v3;
        }
        for (; k < m; k++) {
            float w = wsh[k * 4 + h];
            int s = ssh[k];
            denom += w;
            acc += w * bfu2f(h1b[(size_t)s * C1 + c]);
        }
        __syncthreads();
    }
    float val = acc / denom + b1[c];
    h2in[(size_t)n * C1 + c] = val > 0.f ? val : expm1f(val);
}

// ---------------- GEMM2 + layer-2 attention logits ----------------
#define LDB 260
__global__ __launch_bounds__(256) void k_gemm2(const float* __restrict__ h2in,
                                               const float* __restrict__ W2,
                                               const float* __restrict__ as2, const float* __restrict__ ad2,
                                               float* __restrict__ h2,
                                               float* __restrict__ a_src2, float* __restrict__ a_dst2) {
    __shared__ __align__(16) float ws_t[16 * LDB];  // [col][k]
    __shared__ __align__(16) float hs[16 * LDB];    // [r][k]
    int tid = threadIdx.x;
#pragma unroll
    for (int i = 0; i < 16; i++) {
        int idx = i * 256 + tid;
        int k = idx >> 4, col = idx & 15;
        ws_t[col * LDB + k] = W2[idx];
    }
    int nb = blockIdx.x * 16;
    for (int i = 0; i < 16; i++) {
        int n = nb + i;
        hs[i * LDB + tid] = (n < NN) ? h2in[(size_t)n * C1 + tid] : 0.f;
    }
    __syncthreads();
    int r = tid >> 4, col = tid & 15;
    float acc = 0.f;
    for (int k = 0; k < 256; k += 4) {
        float4 hv = *(const float4*)&hs[r * LDB + k];
        float4 wv = *(const float4*)&ws_t[col * LDB + k];
        acc += hv.x * wv.x + hv.y * wv.y + hv.z * wv.z + hv.w * wv.w;
    }
    float pa = acc * as2[col], pb = acc * ad2[col];
#pragma unroll
    for (int off = 8; off; off >>= 1) {
        pa += __shfl_xor(pa, off, 16);
        pb += __shfl_xor(pb, off, 16);
    }
    int n = nb + r;
    if (n < NN) {
        h2[(size_t)n * NC + col] = acc;
        if (col == 0) { a_src2[n] = pa; a_dst2[n] = pb; }
    }
}

// ---------------- layer-2 aggregation: fused softmax + gather + bias -> out ----------------
__global__ __launch_bounds__(256) void k_agg2(const float* __restrict__ h2,
                                              const int* __restrict__ csr,
                                              const int* __restrict__ row_off, const int* __restrict__ cnt,
                                              const float* __restrict__ a_src2, const float* __restrict__ a_dst2,
                                              const float* __restrict__ b2, float* __restrict__ out) {
    int tid = threadIdx.x;
    int r = tid >> 4, col = tid & 15;
    int n = blockIdx.x * 16 + r;
    if (n >= NN) return;
    float adn = a_dst2[n];
    float es = a_src2[n] + adn;
    es = es >= 0.f ? es : NEG * es;
    float wse = __expf(es);
    float denom = wse;
    float acc = wse * h2[(size_t)n * NC + col];
    int base = row_off[n], deg = cnt[n];
    int k = 0;
    for (; k + 4 <= deg; k += 4) {
        int s0 = csr[base + k + 0], s1 = csr[base + k + 1];
        int s2 = csr[base + k + 2], s3 = csr[base + k + 3];
        float e0 = a_src2[s0] + adn, e1 = a_src2[s1] + adn;
        float e2 = a_src2[s2] + adn, e3 = a_src2[s3] + adn;
        float v0 = h2[(size_t)s0 * NC + col], v1 = h2[(size_t)s1 * NC + col];
        float v2 = h2[(size_t)s2 * NC + col], v3 = h2[(size_t)s3 * NC + col];
        e0 = e0 >= 0.f ? e0 : NEG * e0;
        e1 = e1 >= 0.f ? e1 : NEG * e1;
        e2 = e2 >= 0.f ? e2 : NEG * e2;
        e3 = e3 >= 0.f ? e3 : NEG * e3;
        float w0 = __expf(e0), w1 = __expf(e1), w2 = __expf(e2), w3 = __expf(e3);
        denom += w0; acc += w0 * v0;
        denom += w1; acc += w1 * v1;
        denom += w2; acc += w2 * v2;
        denom += w3; acc += w3 * v3;
    }
    for (; k < deg; k++) {
        int s0 = csr[base + k];
        float e0 = a_src2[s0] + adn;
        e0 = e0 >= 0.f ? e0 : NEG * e0;
        float w0 = __expf(e0);
        denom += w0;
        acc += w0 * h2[(size_t)s0 * NC + col];
    }
    out[(size_t)n * NC + col] = acc / denom + b2[col];
}

extern "C" void kernel_launch(void* const* d_in, const int* in_sizes, int n_in,
                              void* d_out, int out_size, void* d_ws, size_t ws_size,
                              hipStream_t stream) {
    const float* x   = (const float*)d_in[0];
    const int*   ei  = (const int*)d_in[1];
    const int*   esrc = ei;
    const int*   edst = ei + EE;
    const float* W1  = (const float*)d_in[2];
    const float* as1 = (const float*)d_in[3];
    const float* ad1 = (const float*)d_in[4];
    const float* b1  = (const float*)d_in[5];
    const float* W2  = (const float*)d_in[6];
    const float* as2 = (const float*)d_in[7];
    const float* ad2 = (const float*)d_in[8];
    const float* b2  = (const float*)d_in[9];
    float* out = (float*)d_out;

    char* w = (char*)d_ws;
    size_t off = 0;
    auto alloc = [&](size_t bytes) -> void* {
        void* p = w + off;
        off += (bytes + 255) & ~(size_t)255;
        return p;
    };
    unsigned short* h1b = (unsigned short*)alloc((size_t)NN * C1 * 2);
    float* h2in   = (float*)alloc((size_t)NN * C1 * 4);
    int*   csr    = (int*)alloc((size_t)EE * 4);
    float* h2     = (float*)alloc((size_t)NN * NC * 4);
    float* a_src1 = (float*)alloc((size_t)NN * 4 * 4);
    float* a_dst1 = (float*)alloc((size_t)NN * 4 * 4);
    int*   cnt    = (int*)alloc((size_t)NN * 4);
    int*   row_off= (int*)alloc((size_t)NN * 4);
    int*   cursor = (int*)alloc((size_t)NN * 4);
    float* a_src2 = (float*)alloc((size_t)NN * 4);
    float* a_dst2 = (float*)alloc((size_t)NN * 4);
    int*   partial= (int*)alloc(256 * 4);
    __hip_bfloat16* W1t = (__hip_bfloat16*)alloc((size_t)C1 * INCH * 2);

    hipMemsetAsync(cnt, 0, (size_t)NN * 4, stream);

    const int NBLK = (NN + 255) / 256;          // 196
    const int EBLK = (EE + 255) / 256;          // 3125

    k_w1t<<<dim3(INCH / 32, C1 / 32), 256, 0, stream>>>(W1, W1t);
    k_hist<<<EBLK, 256, 0, stream>>>(edst, cnt);
    dim3 g1((NN + BM - 1) / BM, C1 / BN);       // (391, 2)
    k_gemm1<<<g1, 256, 0, stream>>>(x, W1t, as1, ad1, h1b, a_src1, a_dst1);
    k_scan1<<<NBLK, 256, 0, stream>>>(cnt, partial);
    k_scan2<<<1, 256, 0, stream>>>(partial, NBLK);
    k_scan3<<<NBLK, 256, 0, stream>>>(cnt, partial, row_off, cursor);
    k_place<<<EBLK, 256, 0, stream>>>(esrc, edst, cursor, csr);
    k_agg1<<<NN, 256, 0, stream>>>(h1b, csr, row_off, cnt, a_src1, a_dst1, b1, h2in);
    k_gemm2<<<(NN + 15) / 16, 256, 0, stream>>>(h2in, W2, as2, ad2, h2, a_src2, a_dst2);
    k_agg2<<<(NN + 15) / 16, 256, 0, stream>>>(h2, csr, row_off, cnt, a_src2, a_dst2, b2, out);
}

// Round 6
// 406.900 us; speedup vs baseline: 2.5653x; 1.0963x over previous
//
#include <hip/hip_runtime.h>
#include <hip/hip_bf16.h>
#include <math.h>

#define NN 50000
#define EE 800000
#define INCH 512
#define C1 256     // H1*HID
#define NC 16
#define NEG 0.2f

typedef __attribute__((ext_vector_type(8))) short bf16x8;
typedef __attribute__((ext_vector_type(4))) float f32x4;

__device__ inline short f2bf(float f) {
    __hip_bfloat16 h = __float2bfloat16(f);
    return *reinterpret_cast<short*>(&h);
}

__device__ inline void unpack4(uint2 rv, float& v0, float& v1, float& v2, float& v3) {
    v0 = __uint_as_float(rv.x << 16);
    v1 = __uint_as_float(rv.x & 0xFFFF0000u);
    v2 = __uint_as_float(rv.y << 16);
    v3 = __uint_as_float(rv.y & 0xFFFF0000u);
}

// ---------------- W1 transpose + bf16 convert: W1[512,256] f32 -> W1t[256,512] bf16 ----------------
__global__ __launch_bounds__(256) void k_w1t(const float* __restrict__ W1,
                                             __hip_bfloat16* __restrict__ W1t) {
    __shared__ float t[32][33];
    int k0 = blockIdx.x * 32, n0 = blockIdx.y * 32;
    int tx = threadIdx.x & 31, ty = threadIdx.x >> 5;  // ty 0..7
#pragma unroll
    for (int i = 0; i < 4; i++) {
        t[ty + i * 8][tx] = W1[(size_t)(k0 + ty + i * 8) * C1 + n0 + tx];
    }
    __syncthreads();
#pragma unroll
    for (int i = 0; i < 4; i++) {
        W1t[(size_t)(n0 + ty + i * 8) * INCH + k0 + tx] = __float2bfloat16(t[tx][ty + i * 8]);
    }
}

// ---------------- GEMM1 (bf16 MFMA, split-x): h1(bf16) = x @ W1, fused att logits ----------------
#define BM 128
#define BN 128
#define BK 32
#define LDT 40   // bf16 row stride (32 + 8 pad)
__global__ __launch_bounds__(256) void k_gemm1(const float* __restrict__ x,
                                               const __hip_bfloat16* __restrict__ W1t,
                                               const float* __restrict__ as1,
                                               const float* __restrict__ ad1,
                                               unsigned short* __restrict__ h1b,
                                               float* __restrict__ a_src,
                                               float* __restrict__ a_dst) {
    __shared__ __align__(16) short Ah[BM * LDT];
    __shared__ __align__(16) short Al[BM * LDT];
    __shared__ __align__(16) short Bl[BN * LDT];
    int tid = threadIdx.x;
    int wave = tid >> 6, lane = tid & 63;
    int quad = lane >> 4, l16 = lane & 15;
    int wm = wave >> 1, wn = wave & 1;
    int bm = blockIdx.x * BM;
    int bn = blockIdx.y * BN;

    f32x4 acc[4][4];
#pragma unroll
    for (int i = 0; i < 4; i++)
#pragma unroll
        for (int j = 0; j < 4; j++) acc[i][j] = (f32x4){0.f, 0.f, 0.f, 0.f};

    for (int kt = 0; kt < INCH; kt += BK) {
        // stage A (x tile 128x32 f32 -> hi/lo bf16)
#pragma unroll
        for (int i = 0; i < 4; i++) {
            int idx = tid + 256 * i;        // float4 units, 0..1023
            int row = idx >> 3, c4 = idx & 7;
            int m = bm + row; if (m >= NN) m = NN - 1;
            float4 v = *(const float4*)&x[(size_t)m * INCH + kt + c4 * 4];
            uint ux = __float_as_uint(v.x), uy = __float_as_uint(v.y);
            uint uz = __float_as_uint(v.z), uw = __float_as_uint(v.w);
            short4 h4 = make_short4((short)(ux >> 16), (short)(uy >> 16),
                                    (short)(uz >> 16), (short)(uw >> 16));
            float4 fh = make_float4(__uint_as_float(ux & 0xFFFF0000u), __uint_as_float(uy & 0xFFFF0000u),
                                    __uint_as_float(uz & 0xFFFF0000u), __uint_as_float(uw & 0xFFFF0000u));
            short4 l4 = make_short4(f2bf(v.x - fh.x), f2bf(v.y - fh.y),
                                    f2bf(v.z - fh.z), f2bf(v.w - fh.w));
            *(short4*)&Ah[row * LDT + c4 * 4] = h4;
            *(short4*)&Al[row * LDT + c4 * 4] = l4;
        }
        // stage B (W1t tile 128x32 bf16, already converted)
#pragma unroll
        for (int i = 0; i < 2; i++) {
            int idx = tid + 256 * i;        // 8-bf16 units, 0..511
            int row = idx >> 2, c8 = idx & 3;
            float4 v = *(const float4*)(W1t + (size_t)(bn + row) * INCH + kt + c8 * 8);
            *(float4*)&Bl[row * LDT + c8 * 8] = v;
        }
        __syncthreads();
        bf16x8 afh[4], afl[4], bfr[4];
#pragma unroll
        for (int mi = 0; mi < 4; mi++) {
            afh[mi] = *(bf16x8*)&Ah[(wm * 64 + mi * 16 + l16) * LDT + quad * 8];
            afl[mi] = *(bf16x8*)&Al[(wm * 64 + mi * 16 + l16) * LDT + quad * 8];
        }
#pragma unroll
        for (int ni = 0; ni < 4; ni++)
            bfr[ni] = *(bf16x8*)&Bl[(wn * 64 + ni * 16 + l16) * LDT + quad * 8];
#pragma unroll
        for (int mi = 0; mi < 4; mi++)
#pragma unroll
            for (int ni = 0; ni < 4; ni++) {
                acc[mi][ni] = __builtin_amdgcn_mfma_f32_16x16x32_bf16(afl[mi], bfr[ni], acc[mi][ni], 0, 0, 0);
                acc[mi][ni] = __builtin_amdgcn_mfma_f32_16x16x32_bf16(afh[mi], bfr[ni], acc[mi][ni], 0, 0, 0);
            }
        __syncthreads();
    }
    // store h1 as bf16 (C/D layout: col=l16, row=quad*4+r)
#pragma unroll
    for (int mi = 0; mi < 4; mi++) {
        int rowb = bm + wm * 64 + mi * 16 + quad * 4;
#pragma unroll
        for (int r = 0; r < 4; r++) {
            int gm = rowb + r;
            if (gm < NN) {
#pragma unroll
                for (int ni = 0; ni < 4; ni++)
                    h1b[(size_t)gm * C1 + bn + wn * 64 + ni * 16 + l16] =
                        (unsigned short)f2bf(acc[mi][ni][r]);
            }
        }
    }
    // fused attention logits (from f32 accumulators): this wave's 64 cols == one head
    int head = blockIdx.y * 2 + wn;
    float aw[4], dw[4];
#pragma unroll
    for (int ni = 0; ni < 4; ni++) {
        aw[ni] = as1[head * 64 + ni * 16 + l16];
        dw[ni] = ad1[head * 64 + ni * 16 + l16];
    }
#pragma unroll
    for (int mi = 0; mi < 4; mi++) {
#pragma unroll
        for (int r = 0; r < 4; r++) {
            float ps = acc[mi][0][r] * aw[0] + acc[mi][1][r] * aw[1] + acc[mi][2][r] * aw[2] + acc[mi][3][r] * aw[3];
            float pd = acc[mi][0][r] * dw[0] + acc[mi][1][r] * dw[1] + acc[mi][2][r] * dw[2] + acc[mi][3][r] * dw[3];
#pragma unroll
            for (int off = 8; off; off >>= 1) {
                ps += __shfl_xor(ps, off, 16);
                pd += __shfl_xor(pd, off, 16);
            }
            if (l16 == 0) {
                int gm = bm + wm * 64 + mi * 16 + quad * 4 + r;
                if (gm < NN) {
                    a_src[gm * 4 + head] = ps;
                    a_dst[gm * 4 + head] = pd;
                }
            }
        }
    }
}

// ---------------- degree histogram ----------------
__global__ __launch_bounds__(256) void k_hist(const int* __restrict__ edst, int* __restrict__ cnt) {
    int e = blockIdx.x * 256 + threadIdx.x;
    if (e < EE) atomicAdd(&cnt[edst[e]], 1);
}

// ---------------- scan (3-phase exclusive prefix over cnt[50000]) ----------------
__global__ __launch_bounds__(256) void k_scan1(const int* __restrict__ cnt, int* __restrict__ partial) {
    __shared__ int s[256];
    int i = blockIdx.x * 256 + threadIdx.x;
    s[threadIdx.x] = (i < NN) ? cnt[i] : 0;
    __syncthreads();
    for (int off = 128; off; off >>= 1) {
        if (threadIdx.x < off) s[threadIdx.x] += s[threadIdx.x + off];
        __syncthreads();
    }
    if (threadIdx.x == 0) partial[blockIdx.x] = s[0];
}

__global__ __launch_bounds__(256) void k_scan2(int* partial, int nb) {
    __shared__ int s[256];
    int t = threadIdx.x;
    int v = (t < nb) ? partial[t] : 0;
    s[t] = v;
    __syncthreads();
    for (int off = 1; off < 256; off <<= 1) {
        int y = (t >= off) ? s[t - off] : 0;
        __syncthreads();
        s[t] += y;
        __syncthreads();
    }
    if (t < nb) partial[t] = s[t] - v;  // exclusive
}

__global__ __launch_bounds__(256) void k_scan3(const int* __restrict__ cnt, const int* __restrict__ partial,
                                               int* __restrict__ row_off, int* __restrict__ cursor) {
    __shared__ int s[256];
    int t = threadIdx.x;
    int i = blockIdx.x * 256 + t;
    int v = (i < NN) ? cnt[i] : 0;
    s[t] = v;
    __syncthreads();
    for (int off = 1; off < 256; off <<= 1) {
        int y = (t >= off) ? s[t - off] : 0;
        __syncthreads();
        s[t] += y;
        __syncthreads();
    }
    if (i < NN) {
        int o = partial[blockIdx.x] + s[t] - v;
        row_off[i] = o;
        cursor[i] = o;
    }
}

// ---------------- CSR placement (stores SRC node id directly) ----------------
__global__ __launch_bounds__(256) void k_place(const int* __restrict__ esrc, const int* __restrict__ edst,
                                               int* __restrict__ cursor, int* __restrict__ csr) {
    int e = blockIdx.x * 256 + threadIdx.x;
    if (e >= EE) return;
    int d = edst[e];
    int s = esrc[e];
    int pos = atomicAdd(&cursor[d], 1);
    csr[pos] = s;
}

// ---------------- layer-1 aggregation: one wave per node, 4 ch/lane, barrier-free ----------
__global__ __launch_bounds__(256) void k_agg1(const unsigned short* __restrict__ h1b,
                                              const int* __restrict__ csr,
                                              const int* __restrict__ row_off, const int* __restrict__ cnt,
                                              const float* __restrict__ a_src, const float* __restrict__ a_dst,
                                              const float* __restrict__ b1, float* __restrict__ h2in) {
    int tid = threadIdx.x;
    int wv = tid >> 6, lane = tid & 63;
    int n = blockIdx.x * 4 + wv;
    if (n >= NN) return;
    int head = lane >> 4;                       // this lane's head (channels 4*lane..4*lane+3)
    const uint2* rows = (const uint2*)h1b;      // 8B units; row n = n*64 + lane

    float adn = a_dst[n * 4 + head];
    // self loop
    float es = a_src[n * 4 + head] + adn;
    es = fmaxf(es, NEG * es);
    float wse = __expf(es);
    float denom = wse;
    float a0, a1, a2, a3;
    {
        uint2 rv = rows[(size_t)n * 64 + lane];
        float v0, v1, v2, v3;
        unpack4(rv, v0, v1, v2, v3);
        a0 = wse * v0; a1 = wse * v1; a2 = wse * v2; a3 = wse * v3;
    }

    int base = row_off[n], deg = cnt[n];
    for (int c0 = 0; c0 < deg; c0 += 64) {
        int sv = 0;
        if (c0 + lane < deg) sv = csr[base + c0 + lane];
        int m = deg - c0; if (m > 64) m = 64;
        int k = 0;
        for (; k + 4 <= m; k += 4) {
            int s0 = __shfl(sv, k + 0), s1 = __shfl(sv, k + 1);
            int s2 = __shfl(sv, k + 2), s3 = __shfl(sv, k + 3);
            float e0 = a_src[s0 * 4 + head] + adn;
            float e1 = a_src[s1 * 4 + head] + adn;
            float e2 = a_src[s2 * 4 + head] + adn;
            float e3 = a_src[s3 * 4 + head] + adn;
            uint2 r0 = rows[(size_t)s0 * 64 + lane];
            uint2 r1 = rows[(size_t)s1 * 64 + lane];
            uint2 r2 = rows[(size_t)s2 * 64 + lane];
            uint2 r3 = rows[(size_t)s3 * 64 + lane];
            e0 = fmaxf(e0, NEG * e0); e1 = fmaxf(e1, NEG * e1);
            e2 = fmaxf(e2, NEG * e2); e3 = fmaxf(e3, NEG * e3);
            float w0 = __expf(e0), w1 = __expf(e1), w2 = __expf(e2), w3 = __expf(e3);
            float v0, v1, v2, v3;
            unpack4(r0, v0, v1, v2, v3);
            denom += w0; a0 += w0 * v0; a1 += w0 * v1; a2 += w0 * v2; a3 += w0 * v3;
            unpack4(r1, v0, v1, v2, v3);
            denom += w1; a0 += w1 * v0; a1 += w1 * v1; a2 += w1 * v2; a3 += w1 * v3;
            unpack4(r2, v0, v1, v2, v3);
            denom += w2; a0 += w2 * v0; a1 += w2 * v1; a2 += w2 * v2; a3 += w2 * v3;
            unpack4(r3, v0, v1, v2, v3);
            denom += w3; a0 += w3 * v0; a1 += w3 * v1; a2 += w3 * v2; a3 += w3 * v3;
        }
        for (; k < m; k++) {
            int s0 = __shfl(sv, k);
            float e0 = a_src[s0 * 4 + head] + adn;
            uint2 r0 = rows[(size_t)s0 * 64 + lane];
            e0 = fmaxf(e0, NEG * e0);
            float w0 = __expf(e0);
            float v0, v1, v2, v3;
            unpack4(r0, v0, v1, v2, v3);
            denom += w0; a0 += w0 * v0; a1 += w0 * v1; a2 += w0 * v2; a3 += w0 * v3;
        }
    }
    float inv = 1.f / denom;
    float4 bv = *(const float4*)&b1[lane * 4];
    float o0 = a0 * inv + bv.x, o1 = a1 * inv + bv.y;
    float o2 = a2 * inv + bv.z, o3 = a3 * inv + bv.w;
    o0 = o0 > 0.f ? o0 : expm1f(o0);
    o1 = o1 > 0.f ? o1 : expm1f(o1);
    o2 = o2 > 0.f ? o2 : expm1f(o2);
    o3 = o3 > 0.f ? o3 : expm1f(o3);
    *(float4*)&h2in[(size_t)n * C1 + lane * 4] = make_float4(o0, o1, o2, o3);
}

// ---------------- GEMM2 + layer-2 attention logits ----------------
#define LDB 260
__global__ __launch_bounds__(256) void k_gemm2(const float* __restrict__ h2in,
                                               const float* __restrict__ W2,
                                               const float* __restrict__ as2, const float* __restrict__ ad2,
                                               float* __restrict__ h2,
                                               float* __restrict__ a_src2, float* __restrict__ a_dst2) {
    __shared__ __align__(16) float ws_t[16 * LDB];  // [col][k]
    __shared__ __align__(16) float hs[16 * LDB];    // [r][k]
    int tid = threadIdx.x;
#pragma unroll
    for (int i = 0; i < 16; i++) {
        int idx = i * 256 + tid;
        int k = idx >> 4, col = idx & 15;
        ws_t[col * LDB + k] = W2[idx];
    }
    int nb = blockIdx.x * 16;
    for (int i = 0; i < 16; i++) {
        int n = nb + i;
        hs[i * LDB + tid] = (n < NN) ? h2in[(size_t)n * C1 + tid] : 0.f;
    }
    __syncthreads();
    int r = tid >> 4, col = tid & 15;
    float acc = 0.f;
    for (int k = 0; k < 256; k += 4) {
        float4 hv = *(const float4*)&hs[r * LDB + k];
        float4 wv = *(const float4*)&ws_t[col * LDB + k];
        acc += hv.x * wv.x + hv.y * wv.y + hv.z * wv.z + hv.w * wv.w;
    }
    float pa = acc * as2[col], pb = acc * ad2[col];
#pragma unroll
    for (int off = 8; off; off >>= 1) {
        pa += __shfl_xor(pa, off, 16);
        pb += __shfl_xor(pb, off, 16);
    }
    int n = nb + r;
    if (n < NN) {
        h2[(size_t)n * NC + col] = acc;
        if (col == 0) { a_src2[n] = pa; a_dst2[n] = pb; }
    }
}

// ---------------- layer-2 aggregation: fused softmax + gather + bias -> out ----------------
__global__ __launch_bounds__(256) void k_agg2(const float* __restrict__ h2,
                                              const int* __restrict__ csr,
                                              const int* __restrict__ row_off, const int* __restrict__ cnt,
                                              const float* __restrict__ a_src2, const float* __restrict__ a_dst2,
                                              const float* __restrict__ b2, float* __restrict__ out) {
    int tid = threadIdx.x;
    int r = tid >> 4, col = tid & 15;
    int n = blockIdx.x * 16 + r;
    if (n >= NN) return;
    float adn = a_dst2[n];
    float es = a_src2[n] + adn;
    es = fmaxf(es, NEG * es);
    float wse = __expf(es);
    float denom = wse;
    float acc = wse * h2[(size_t)n * NC + col];
    int base = row_off[n], deg = cnt[n];
    int k = 0;
    for (; k + 4 <= deg; k += 4) {
        int s0 = csr[base + k + 0], s1 = csr[base + k + 1];
        int s2 = csr[base + k + 2], s3 = csr[base + k + 3];
        float e0 = a_src2[s0] + adn, e1 = a_src2[s1] + adn;
        float e2 = a_src2[s2] + adn, e3 = a_src2[s3] + adn;
        float v0 = h2[(size_t)s0 * NC + col], v1 = h2[(size_t)s1 * NC + col];
        float v2 = h2[(size_t)s2 * NC + col], v3 = h2[(size_t)s3 * NC + col];
        e0 = fmaxf(e0, NEG * e0); e1 = fmaxf(e1, NEG * e1);
        e2 = fmaxf(e2, NEG * e2); e3 = fmaxf(e3, NEG * e3);
        float w0 = __expf(e0), w1 = __expf(e1), w2 = __expf(e2), w3 = __expf(e3);
        denom += w0; acc += w0 * v0;
        denom += w1; acc += w1 * v1;
        denom += w2; acc += w2 * v2;
        denom += w3; acc += w3 * v3;
    }
    for (; k < deg; k++) {
        int s0 = csr[base + k];
        float e0 = a_src2[s0] + adn;
        e0 = fmaxf(e0, NEG * e0);
        float w0 = __expf(e0);
        denom += w0;
        acc += w0 * h2[(size_t)s0 * NC + col];
    }
    out[(size_t)n * NC + col] = acc / denom + b2[col];
}

extern "C" void kernel_launch(void* const* d_in, const int* in_sizes, int n_in,
                              void* d_out, int out_size, void* d_ws, size_t ws_size,
                              hipStream_t stream) {
    const float* x   = (const float*)d_in[0];
    const int*   ei  = (const int*)d_in[1];
    const int*   esrc = ei;
    const int*   edst = ei + EE;
    const float* W1  = (const float*)d_in[2];
    const float* as1 = (const float*)d_in[3];
    const float* ad1 = (const float*)d_in[4];
    const float* b1  = (const float*)d_in[5];
    const float* W2  = (const float*)d_in[6];
    const float* as2 = (const float*)d_in[7];
    const float* ad2 = (const float*)d_in[8];
    const float* b2  = (const float*)d_in[9];
    float* out = (float*)d_out;

    char* w = (char*)d_ws;
    size_t off = 0;
    auto alloc = [&](size_t bytes) -> void* {
        void* p = w + off;
        off += (bytes + 255) & ~(size_t)255;
        return p;
    };
    unsigned short* h1b = (unsigned short*)alloc((size_t)NN * C1 * 2);
    float* h2in   = (float*)alloc((size_t)NN * C1 * 4);
    int*   csr    = (int*)alloc((size_t)EE * 4);
    float* h2     = (float*)alloc((size_t)NN * NC * 4);
    float* a_src1 = (float*)alloc((size_t)NN * 4 * 4);
    float* a_dst1 = (float*)alloc((size_t)NN * 4 * 4);
    int*   cnt    = (int*)alloc((size_t)NN * 4);
    int*   row_off= (int*)alloc((size_t)NN * 4);
    int*   cursor = (int*)alloc((size_t)NN * 4);
    float* a_src2 = (float*)alloc((size_t)NN * 4);
    float* a_dst2 = (float*)alloc((size_t)NN * 4);
    int*   partial= (int*)alloc(256 * 4);
    __hip_bfloat16* W1t = (__hip_bfloat16*)alloc((size_t)C1 * INCH * 2);

    hipMemsetAsync(cnt, 0, (size_t)NN * 4, stream);

    const int NBLK = (NN + 255) / 256;          // 196
    const int EBLK = (EE + 255) / 256;          // 3125

    k_w1t<<<dim3(INCH / 32, C1 / 32), 256, 0, stream>>>(W1, W1t);
    k_hist<<<EBLK, 256, 0, stream>>>(edst, cnt);
    dim3 g1((NN + BM - 1) / BM, C1 / BN);       // (391, 2)
    k_gemm1<<<g1, 256, 0, stream>>>(x, W1t, as1, ad1, h1b, a_src1, a_dst1);
    k_scan1<<<NBLK, 256, 0, stream>>>(cnt, partial);
    k_scan2<<<1, 256, 0, stream>>>(partial, NBLK);
    k_scan3<<<NBLK, 256, 0, stream>>>(cnt, partial, row_off, cursor);
    k_place<<<EBLK, 256, 0, stream>>>(esrc, edst, cursor, csr);
    k_agg1<<<(NN + 3) / 4, 256, 0, stream>>>(h1b, csr, row_off, cnt, a_src1, a_dst1, b1, h2in);
    k_gemm2<<<(NN + 15) / 16, 256, 0, stream>>>(h2in, W2, as2, ad2, h2, a_src2, a_dst2);
    k_agg2<<<(NN + 15) / 16, 256, 0, stream>>>(h2, csr, row_off, cnt, a_src2, a_dst2, b2, out);
}